// Round 5
// baseline (237.932 us; speedup 1.0000x reference)
//
#include <hip/hip_runtime.h>
#include <hip/hip_bf16.h>

#define DM   1024
#define HEADS 16
#define DH    64
#define SEQ  2048
#define BATCH   2
#define LOG2E 1.44269504088896f

typedef __attribute__((ext_vector_type(8))) short short8;
typedef __attribute__((ext_vector_type(4))) short bf16x4;
typedef __attribute__((ext_vector_type(4))) float floatx4;
typedef __attribute__((ext_vector_type(16))) float floatx16;

__device__ __forceinline__ short f2b(float f) {
    union { float f; unsigned u; } v; v.f = f;
    unsigned r = v.u + 0x7FFFu + ((v.u >> 16) & 1u);
    return (short)(r >> 16);
}

#if __has_builtin(__builtin_amdgcn_exp2f)
__device__ __forceinline__ float fexp2(float x) { return __builtin_amdgcn_exp2f(x); }
#else
__device__ __forceinline__ float fexp2(float x) { return exp2f(x); }
#endif

__device__ __forceinline__ void async_copy16(const short* gsrc, short* ldst) {
    __builtin_amdgcn_global_load_lds(
        (const __attribute__((address_space(1))) void*)gsrc,
        (__attribute__((address_space(3))) void*)ldst,
        16, 0, 0);
}

// pack two f32 -> one u32 of 2 bf16 (lo,hi)
__device__ __forceinline__ unsigned pk2(float lo, float hi) {
    union { __hip_bfloat162 h; unsigned u; } x;
    x.h = __float22bfloat162_rn(make_float2(lo, hi));
    return x.u;
}

// v_permlane32_swap_b32: a' = {a.lo, b.lo}, b' = {a.hi, b.hi} (lane-halves)
__device__ __forceinline__ void pl32swap(unsigned& a, unsigned& b) {
    asm volatile("v_permlane32_swap_b32 %0, %1" : "+v"(a), "+v"(b));
}

// Fused fp32->bf16 conversion of x, Wq, Wk, Wv, Wo + mask-add table (log2 domain).
__global__ __launch_bounds__(256) void cvt_all(const float* __restrict__ x,
        const float* __restrict__ wq, const float* __restrict__ wk,
        const float* __restrict__ wv, const float* __restrict__ wo,
        const float* __restrict__ mask,
        short* __restrict__ xb, short* __restrict__ wqkv, short* __restrict__ wob,
        float* __restrict__ maddg)
{
    const int b = blockIdx.x;
    if (b >= 8192) {            // mask prep: maddg = (1-mask) * (-1e5 * log2e)
        const int bb = b - 8192;
        const float* mrow = mask + (size_t)bb * SEQ;
        float* mg = maddg + (size_t)bb * SEQ;
#pragma unroll
        for (int i = 0; i < 8; ++i) {
            const int idx = threadIdx.x * 8 + i;
            mg[idx] = (1.f - mrow[idx]) * (-100000.f * LOG2E);
        }
        return;
    }
    const float* src; short* dst; int idx;
    if (b < 4096)      { src = x;  dst = xb;                idx = b; }
    else if (b < 5120) { src = wq; dst = wqkv;              idx = b - 4096; }
    else if (b < 6144) { src = wk; dst = wqkv + (1 << 20);  idx = b - 5120; }
    else if (b < 7168) { src = wv; dst = wqkv + (2 << 20);  idx = b - 6144; }
    else               { src = wo; dst = wob;               idx = b - 7168; }
    const int i = idx * 256 + threadIdx.x;
    floatx4 v = ((const floatx4*)src)[i];
    bf16x4 o;
    o.x = f2b(v.x); o.y = f2b(v.y); o.z = f2b(v.z); o.w = f2b(v.w);
    ((bf16x4*)dst)[i] = o;
}

// Fused QKV GEMM (m97 structure, 128x128 tile, BK=32). B rows: Wq|Wk|Wv.
__global__ __launch_bounds__(256) void gemm_qkv(const short* __restrict__ A,
        const short* __restrict__ B,
        const float* __restrict__ bq, const float* __restrict__ bk,
        const float* __restrict__ bv,
        short* __restrict__ qw, short* __restrict__ kw, short* __restrict__ vw)
{
    __shared__ short As[128 * 32];
    __shared__ short Bs[128 * 32];
    const int m0 = blockIdx.x * 128, n0 = blockIdx.y * 128;
    const int w = threadIdx.x >> 6, lane = threadIdx.x & 63;
    const int l16 = lane & 15, quad = lane >> 4;
    const int wm = w >> 1, wn = w & 1;
    const int lr = lane >> 2, lc = (lane & 3) * 8;

    floatx4 acc[4][4];
#pragma unroll
    for (int i = 0; i < 4; ++i)
#pragma unroll
        for (int j = 0; j < 4; ++j) acc[i][j] = (floatx4){0.f, 0.f, 0.f, 0.f};

    for (int kt = 0; kt < DM / 32; ++kt) {
        const int k0 = kt * 32;
        __syncthreads();
        async_copy16(A + (size_t)(m0 + w * 32 + lr) * DM + k0 + lc,      &As[w * 1024]);
        async_copy16(A + (size_t)(m0 + w * 32 + 16 + lr) * DM + k0 + lc, &As[w * 1024 + 512]);
        async_copy16(B + (size_t)(n0 + w * 32 + lr) * DM + k0 + lc,      &Bs[w * 1024]);
        async_copy16(B + (size_t)(n0 + w * 32 + 16 + lr) * DM + k0 + lc, &Bs[w * 1024 + 512]);
        __syncthreads();

        short8 af[4], bf[4];
#pragma unroll
        for (int i = 0; i < 4; ++i)
            af[i] = *(const short8*)&As[(wm * 64 + i * 16 + l16) * 32 + quad * 8];
#pragma unroll
        for (int j = 0; j < 4; ++j)
            bf[j] = *(const short8*)&Bs[(wn * 64 + j * 16 + l16) * 32 + quad * 8];
#pragma unroll
        for (int i = 0; i < 4; ++i)
#pragma unroll
            for (int j = 0; j < 4; ++j)
                acc[i][j] = __builtin_amdgcn_mfma_f32_16x16x32_bf16(af[i], bf[j], acc[i][j], 0, 0, 0);
    }

    const int m_base = m0 + wm * 64 + quad * 4;
#pragma unroll
    for (int j = 0; j < 4; ++j) {
        const int nb = n0 + wn * 64 + j * 16;
        const int t = nb >> 10;
        const int nn = (nb & 1023) + l16;
        const int h = nn >> 6, dh = nn & 63;
        const float* bias = (t == 0) ? bq : (t == 1) ? bk : bv;
        short* dst = (t == 0) ? qw : (t == 1) ? kw : vw;
        const float mulf = (t == 0) ? (0.125f * LOG2E) : 1.0f;
        const float bvv = bias[nn];
#pragma unroll
        for (int i = 0; i < 4; ++i)
#pragma unroll
            for (int r = 0; r < 4; ++r) {
                const int m = m_base + i * 16 + r;
                const int b = m >> 11, s = m & (SEQ - 1);
                dst[(((size_t)(b * HEADS + h)) * SEQ + s) * DH + dh] =
                    f2b((acc[i][j][r] + bvv) * mulf);
            }
    }
}

// v [b,h,s,dh] -> vt [b,h,dh,s], 64x64 LDS tiles (coalesced both sides)
__global__ __launch_bounds__(256) void transpose_v(const short* __restrict__ v,
                                                   short* __restrict__ vt)
{
    __shared__ short tl[64][72];
    const int st = blockIdx.x;
    const int bh = blockIdx.y;
    const int t = threadIdx.x;
    const int row = t >> 2, off = (t & 3) * 16;
    const short* vp = v + ((size_t)bh * SEQ + st * 64 + row) * DH + off;
    *(short8*)&tl[row][off]     = *(const short8*)vp;
    *(short8*)&tl[row][off + 8] = *(const short8*)(vp + 8);
    __syncthreads();
    short8 o0, o1;
#pragma unroll
    for (int j = 0; j < 8; ++j) { o0[j] = tl[off + j][row]; o1[j] = tl[off + 8 + j][row]; }
    short* op = vt + ((size_t)bh * DH + row) * SEQ + st * 64 + off;
    *(short8*)op = o0;
    *(short8*)(op + 8) = o1;
}

// Flash attention, 32x32x16 MFMA formulation.
// ROUND-4 CHANGE: in-register P via permlane32_swap (T12) — p_lds round-trip
// and barrier B3 eliminated.
//  - 2 waves/block (128 thr), each wave owns 32 qrows x ALL 64 keys of the
//    tile: S^T = K Q^T computed for both 32-key blocks (8 MFMA), so the full
//    P row lives in the wave's registers. PV B-frags are built in-register:
//    for groups (g0=2k',g1=2k'+1): swap(w0[g0],w0[g1]), swap(w1[g0],w1[g1])
//    -> (S0,S2),(S1,S3); bp = [S0,S1,S2,S3]. Byte-identical to what the old
//    p_lds path delivered (C/D layout m74/m101: col=lane&31 = qrow,
//    row=(reg&3)+8*(reg>>2)+4*(lane>>5) = key).
//  - l fully lane-local now: l_run + shfl_xor(32) at the end. l_fin gone.
//  - LDS = K2(16K)+V2(16K) = 32768B. p_lds gone. 2 barriers/iter (was 3).
//  - grid unchanged 1024 blocks = 4/CU; 8 (fatter) waves/CU.
//  - staging: 8 copies/thread, double-buffered, counted vmcnt(8); mask md
//    loads issued before staging (sched_barrier pinned) so the window is
//    exactly the 8 new copies.
__global__ __launch_bounds__(128) void attn_kernel(const short* __restrict__ q,
        const short* __restrict__ k, const short* __restrict__ vt,
        const float* __restrict__ maddg, short* __restrict__ ctx)
{
    const int id    = blockIdx.x;
    const int qtile = id >> 5;             // id = qtile*32 + bh
    const int bh    = id & 31;
    const int bidx  = bh >> 4;
    const int wave = threadIdx.x >> 6, lane = threadIdx.x & 63;
    const int l32 = lane & 31, half = lane >> 5;

    // LDS arena (shorts), 16384 shorts = 32768 B:
    //  [    0.. 4096) k buf0   [ 4096.. 8192) k buf1
    //  [ 8192..12288) v buf0   [12288..16384) v buf1
    //  epilogue: Ct = shorts [0..4608) aliases retired K bufs
    __shared__ __align__(16) short smem[16384];
    short* Ct = smem;

    const short* kbase0 = k  + (size_t)bh * SEQ * DH;
    const short* vbase0 = vt + (size_t)bh * DH * SEQ;
    const float* mrow   = maddg + (size_t)bidx * SEQ;

    // Q B-frags: B[n=qrow=l32][k=dh = kk*16 + half*8 + j]
    const int qrow = qtile * 64 + wave * 32 + l32;
    const short* qbase = q + ((size_t)bh * SEQ + qrow) * DH;
    short8 b_q[4];
#pragma unroll
    for (int kk = 0; kk < 4; ++kk)
        b_q[kk] = *(const short8*)(qbase + kk * 16 + half * 8);

    floatx16 oacc[2];
#pragma unroll
    for (int db = 0; db < 2; ++db)
#pragma unroll
        for (int r = 0; r < 16; ++r) oacc[db][r] = 0.f;
    float l_run = 0.f;

    // staging geometry: 512 chunks/tile/array, 128 threads -> 4 chunks each
    int srw[4], gg[4];
#pragma unroll
    for (int i = 0; i < 4; ++i) {
        const int slot = i * 128 + threadIdx.x;
        srw[i] = slot >> 3;
        gg[i]  = (slot & 7) ^ (srw[i] & 7);
    }

    const int prow = wave * 32 + l32;      // this lane's qrow (local 0..63)
    const int lsw  = l32 & 7;              // row-XOR swizzle key (k & v reads)

    // stage K/V tile kt into buffer buf (8 copies/thread: 4xK, 4xV)
    auto stage_kv = [&](int buf, int kt) {
        const short* kbase = kbase0 + (size_t)(kt * 64) * DH;
        const short* vbase = vbase0 + kt * 64;
        const int ko = buf << 12;
        const int vo = 8192 + (buf << 12);
#pragma unroll
        for (int i = 0; i < 4; ++i) {
            async_copy16(kbase + srw[i] * DH + gg[i] * 8,
                         &smem[ko + (i * 128 + wave * 64) * 8]);
            async_copy16(vbase + (size_t)srw[i] * SEQ + gg[i] * 8,
                         &smem[vo + (i * 128 + wave * 64) * 8]);
        }
    };

    // prologue: tile 0 into buf 0 (drained by iter-0's vmcnt(8)).
    stage_kv(0, 0);

    int cur = 0;
    for (int kt = 0; kt < SEQ / 64; ++kt) {
        // B1: prev-iter reads of buf[cur^1] complete
        asm volatile("" ::: "memory");
        __builtin_amdgcn_s_barrier();

        // mask C-init loads (global, VGPR): issued BEFORE staging so the
        // counted vmcnt(8) below drains them with prev-tile copies.
        floatx4 md[2][4];
#pragma unroll
        for (int kb = 0; kb < 2; ++kb)
#pragma unroll
            for (int g = 0; g < 4; ++g)
                md[kb][g] = *(const floatx4*)&mrow[kt * 64 + kb * 32 + 8 * g + 4 * half];
        __builtin_amdgcn_sched_barrier(0);   // pin: md loads before stage copies

        if (kt + 1 < SEQ / 64) {
            stage_kv(cur ^ 1, kt + 1);
            asm volatile("s_waitcnt vmcnt(8)" ::: "memory");
        } else {
            asm volatile("s_waitcnt vmcnt(0)" ::: "memory");
        }
        __builtin_amdgcn_s_barrier();      // B2: buf[cur] + md landed

        // S^T = K Q^T (log2 domain), both 32-key blocks, C init = mask
        floatx16 sf[2];
#pragma unroll
        for (int kb = 0; kb < 2; ++kb)
#pragma unroll
            for (int g = 0; g < 4; ++g)
#pragma unroll
                for (int r = 0; r < 4; ++r) sf[kb][g * 4 + r] = md[kb][g][r];
        {
            const int ko = cur << 12;
#pragma unroll
            for (int kb = 0; kb < 2; ++kb) {
                const int krow = kb * 32 + l32;
#pragma unroll
                for (int kk = 0; kk < 4; ++kk) {
                    const int c = kk * 2 + half;
                    short8 a = *(const short8*)&smem[ko + krow * 64 + ((c ^ lsw) * 8)];
                    sf[kb] = __builtin_amdgcn_mfma_f32_32x32x16_bf16(a, b_q[kk], sf[kb], 0, 0, 0);
                }
            }
        }

        // softmax: p = exp2(min(s,40)); pack to bf16 words per group
        unsigned w0[2][4], w1[2][4];
        float lsum = 0.f;
#pragma unroll
        for (int kb = 0; kb < 2; ++kb)
#pragma unroll
            for (int g = 0; g < 4; ++g) {
                const float p0 = fexp2(fminf(sf[kb][g * 4 + 0], 40.f));
                const float p1 = fexp2(fminf(sf[kb][g * 4 + 1], 40.f));
                const float p2 = fexp2(fminf(sf[kb][g * 4 + 2], 40.f));
                const float p3 = fexp2(fminf(sf[kb][g * 4 + 3], 40.f));
                lsum += (p0 + p1) + (p2 + p3);
                w0[kb][g] = pk2(p0, p1);
                w1[kb][g] = pk2(p2, p3);
            }
        l_run += lsum;

        // in-register P exchange: per (kb, k'): groups g0=2k', g1=2k'+1
        //   swap(w0[g0],w0[g1]) -> (S0,S2); swap(w1[g0],w1[g1]) -> (S1,S3)
#pragma unroll
        for (int kb = 0; kb < 2; ++kb)
#pragma unroll
            for (int kp = 0; kp < 2; ++kp) {
                pl32swap(w0[kb][2 * kp], w0[kb][2 * kp + 1]);
                pl32swap(w1[kb][2 * kp], w1[kb][2 * kp + 1]);
            }

        // O^T += V^T P^T : A=V^T[dh][key], B from registers, 8 MFMA
        {
            const int vo = 8192 + (cur << 12);
#pragma unroll
            for (int db = 0; db < 2; ++db) {
                const int vrow = db * 32 + l32;    // dh row
#pragma unroll
                for (int kk = 0; kk < 4; ++kk) {
                    const int c = kk * 2 + half;
                    short8 av = *(const short8*)&smem[vo + vrow * 64 + ((c ^ lsw) * 8)];
                    const int kb = kk >> 1, kp = kk & 1;
                    union { unsigned u[4]; short8 v; } bu;
                    bu.u[0] = w0[kb][2 * kp];
                    bu.u[1] = w1[kb][2 * kp];
                    bu.u[2] = w0[kb][2 * kp + 1];
                    bu.u[3] = w1[kb][2 * kp + 1];
                    oacc[db] = __builtin_amdgcn_mfma_f32_32x32x16_bf16(av, bu.v, oacc[db], 0, 0, 0);
                }
            }
        }
        cur ^= 1;
    }

    // E1: loop fully done; K-buffer region retires for Ct reuse
    asm volatile("" ::: "memory");
    __builtin_amdgcn_s_barrier();

    // l: halves of the wave hold complementary key-subsets of the same qrow
    const float rl = 1.f / (l_run + __shfl_xor(l_run, 32));

    // epilogue: O^T[dh][qrow] / l -> Ct[qrow][dh] -> coalesced global stores
    const int h = bh & 15, bb = bh >> 4;
#pragma unroll
    for (int db = 0; db < 2; ++db)
#pragma unroll
        for (int g = 0; g < 4; ++g) {
            bf16x4 p;
            p.x = f2b(oacc[db][g * 4 + 0] * rl);
            p.y = f2b(oacc[db][g * 4 + 1] * rl);
            p.z = f2b(oacc[db][g * 4 + 2] * rl);
            p.w = f2b(oacc[db][g * 4 + 3] * rl);
            const int dh = db * 32 + 8 * g + 4 * half;  // row=(reg&3)+8g+4*half
            *(bf16x4*)&Ct[prow * 72 + dh] = p;
        }
    __syncthreads();
    {
        const int row = threadIdx.x >> 1, off = (threadIdx.x & 1) * 32;
        short* gp = ctx + ((size_t)(bb * SEQ + qtile * 64 + row)) * DM + h * 64 + off;
#pragma unroll
        for (int j = 0; j < 4; ++j)
            *(short8*)(gp + 8 * j) = *(const short8*)&Ct[row * 72 + off + 8 * j];
    }
}

// Output GEMM + bias + residual (fp32 out into d_out). 128x64 tile, 2 blocks/CU.
__global__ __launch_bounds__(256) void gemm_o(const short* __restrict__ A,
        const short* __restrict__ B, const float* __restrict__ bo,
        const float* __restrict__ xin, float* __restrict__ out)
{
    __shared__ short As[128 * 32];
    __shared__ short Bs[64 * 32];
    const int m0 = blockIdx.x * 128, n0 = blockIdx.y * 64;
    const int w = threadIdx.x >> 6, lane = threadIdx.x & 63;
    const int l16 = lane & 15, quad = lane >> 4;
    const int wm = w >> 1, wn = w & 1;     // wave: 64 rows x 32 cols

    floatx4 acc[4][2];
#pragma unroll
    for (int i = 0; i < 4; ++i)
#pragma unroll
        for (int j = 0; j < 2; ++j) acc[i][j] = (floatx4){0.f, 0.f, 0.f, 0.f};

    const int c0 = w * 64 + lane;

    for (int kt = 0; kt < DM / 32; ++kt) {
        const int k0 = kt * 32;
        __syncthreads();
        {
            const int ra0 = c0 >> 2,          ca0 = (c0 & 3) * 8;
            const int ra1 = (256 + c0) >> 2,  ca1 = (c0 & 3) * 8;
            async_copy16(A + (size_t)(m0 + ra0) * DM + k0 + ca0, &As[(w * 64) * 8]);
            async_copy16(A + (size_t)(m0 + ra1) * DM + k0 + ca1, &As[(256 + w * 64) * 8]);
            const int rb = c0 >> 2, cb = (c0 & 3) * 8;
            async_copy16(B + (size_t)(n0 + rb) * DM + k0 + cb,   &Bs[(w * 64) * 8]);
        }
        __syncthreads();

        short8 af[4], bf[2];
#pragma unroll
        for (int i = 0; i < 4; ++i)
            af[i] = *(const short8*)&As[(wm * 64 + i * 16 + l16) * 32 + quad * 8];
#pragma unroll
        for (int j = 0; j < 2; ++j)
            bf[j] = *(const short8*)&Bs[(wn * 32 + j * 16 + l16) * 32 + quad * 8];
#pragma unroll
        for (int i = 0; i < 4; ++i)
#pragma unroll
            for (int j = 0; j < 2; ++j)
                acc[i][j] = __builtin_amdgcn_mfma_f32_16x16x32_bf16(af[i], bf[j], acc[i][j], 0, 0, 0);
    }

    const int m_base = m0 + wm * 64 + quad * 4;
#pragma unroll
    for (int j = 0; j < 2; ++j) {
        const int n = n0 + wn * 32 + j * 16 + l16;
        const float bvv = bo[n];
#pragma unroll
        for (int i = 0; i < 4; ++i)
#pragma unroll
            for (int r = 0; r < 4; ++r) {
                const int m = m_base + i * 16 + r;
                const size_t idx = (size_t)m * DM + n;
                out[idx] = acc[i][j][r] + bvv + xin[idx];
            }
    }
}

__global__ __launch_bounds__(256) void ln_kernel(float* __restrict__ y,
        const float* __restrict__ gamma, const float* __restrict__ beta)
{
    const int row = blockIdx.x;
    const int t = threadIdx.x;
    const int wave = t >> 6, lane = t & 63;
    const floatx4 v = ((const floatx4*)(y + (size_t)row * DM))[t];
    float s  = v.x + v.y + v.z + v.w;
    float q2 = v.x * v.x + v.y * v.y + v.z * v.z + v.w * v.w;
#pragma unroll
    for (int off = 1; off < 64; off <<= 1) {
        s  += __shfl_xor(s, off);
        q2 += __shfl_xor(q2, off);
    }
    __shared__ float rs[4], rq[4];
    if (lane == 0) { rs[wave] = s; rq[wave] = q2; }
    __syncthreads();
    const float S  = rs[0] + rs[1] + rs[2] + rs[3];
    const float Q2 = rq[0] + rq[1] + rq[2] + rq[3];
    const float mu = S * (1.f / DM);
    float var = Q2 * (1.f / DM) - mu * mu;
    var = fmaxf(var, 0.f);
    const float rstd = rsqrtf(var + 1e-12f);
    const floatx4 g = ((const floatx4*)gamma)[t];
    const floatx4 bt = ((const floatx4*)beta)[t];
    floatx4 o;
    o.x = (v.x - mu) * rstd * g.x + bt.x;
    o.y = (v.y - mu) * rstd * g.y + bt.y;
    o.z = (v.z - mu) * rstd * g.z + bt.z;
    o.w = (v.w - mu) * rstd * g.w + bt.w;
    ((floatx4*)(y + (size_t)row * DM))[t] = o;
}

extern "C" void kernel_launch(void* const* d_in, const int* in_sizes, int n_in,
                              void* d_out, int out_size, void* d_ws, size_t ws_size,
                              hipStream_t stream) {
    const float* x     = (const float*)d_in[0];
    const float* mask  = (const float*)d_in[1];
    const float* Wq    = (const float*)d_in[2];
    const float* bq    = (const float*)d_in[3];
    const float* Wk    = (const float*)d_in[4];
    const float* bk    = (const float*)d_in[5];
    const float* Wv    = (const float*)d_in[6];
    const float* bv    = (const float*)d_in[7];
    const float* Wo    = (const float*)d_in[8];
    const float* bo    = (const float*)d_in[9];
    const float* gamma = (const float*)d_in[10];
    const float* beta  = (const float*)d_in[11];
    float* out = (float*)d_out;

    const size_t NTOK = (size_t)BATCH * SEQ * DM;       // 4M
    const size_t WSZ  = (size_t)DM * DM;                // 1M
    short* xb   = (short*)d_ws;          // 4M shorts
    short* wqkv = xb + NTOK;             // 3M
    short* wob  = wqkv + 3 * WSZ;        // 1M
    short* qw   = wob + WSZ;             // 4M
    short* kw   = qw + NTOK;             // 4M
    short* vw   = kw + NTOK;             // 4M (natural V; aliased as ctx)
    short* vtw  = vw + NTOK;             // 4M (V transposed)
    short* ctxw = vw;
    float* maddg = (float*)(vtw + NTOK); // 4096 floats

    dim3 blk(256);
    cvt_all<<<dim3(8194), blk, 0, stream>>>(x, Wq, Wk, Wv, Wo, mask, xb, wqkv, wob, maddg);
    gemm_qkv<<<dim3(32, 24), blk, 0, stream>>>(xb, wqkv, bq, bk, bv, qw, kw, vw);
    transpose_v<<<dim3(SEQ / 64, BATCH * HEADS), blk, 0, stream>>>(vw, vtw);
    attn_kernel<<<dim3(32 * 32), dim3(128), 0, stream>>>(qw, kw, vtw, maddg, ctxw);
    gemm_o<<<dim3(32, 16), blk, 0, stream>>>(ctxw, wob, bo, x, out);
    ln_kernel<<<BATCH * SEQ, blk, 0, stream>>>(out, gamma, beta);
}

// Round 6
// 230.547 us; speedup vs baseline: 1.0320x; 1.0320x over previous
//
#include <hip/hip_runtime.h>
#include <hip/hip_bf16.h>

#define DM   1024
#define HEADS 16
#define DH    64
#define SEQ  2048
#define BATCH   2
#define LOG2E 1.44269504088896f

typedef __attribute__((ext_vector_type(8))) short short8;
typedef __attribute__((ext_vector_type(4))) short bf16x4;
typedef __attribute__((ext_vector_type(4))) float floatx4;
typedef __attribute__((ext_vector_type(16))) float floatx16;

__device__ __forceinline__ short f2b(float f) {
    union { float f; unsigned u; } v; v.f = f;
    unsigned r = v.u + 0x7FFFu + ((v.u >> 16) & 1u);
    return (short)(r >> 16);
}

#if __has_builtin(__builtin_amdgcn_exp2f)
__device__ __forceinline__ float fexp2(float x) { return __builtin_amdgcn_exp2f(x); }
#else
__device__ __forceinline__ float fexp2(float x) { return exp2f(x); }
#endif

__device__ __forceinline__ void async_copy16(const short* gsrc, short* ldst) {
    __builtin_amdgcn_global_load_lds(
        (const __attribute__((address_space(1))) void*)gsrc,
        (__attribute__((address_space(3))) void*)ldst,
        16, 0, 0);
}

// Fused fp32->bf16 conversion of x, Wq, Wk, Wv, Wo + mask-add table (log2 domain).
__global__ __launch_bounds__(256) void cvt_all(const float* __restrict__ x,
        const float* __restrict__ wq, const float* __restrict__ wk,
        const float* __restrict__ wv, const float* __restrict__ wo,
        const float* __restrict__ mask,
        short* __restrict__ xb, short* __restrict__ wqkv, short* __restrict__ wob,
        float* __restrict__ maddg)
{
    const int b = blockIdx.x;
    if (b >= 8192) {            // mask prep: maddg = (1-mask) * (-1e5 * log2e)
        const int bb = b - 8192;
        const float* mrow = mask + (size_t)bb * SEQ;
        float* mg = maddg + (size_t)bb * SEQ;
#pragma unroll
        for (int i = 0; i < 8; ++i) {
            const int idx = threadIdx.x * 8 + i;
            mg[idx] = (1.f - mrow[idx]) * (-100000.f * LOG2E);
        }
        return;
    }
    const float* src; short* dst; int idx;
    if (b < 4096)      { src = x;  dst = xb;                idx = b; }
    else if (b < 5120) { src = wq; dst = wqkv;              idx = b - 4096; }
    else if (b < 6144) { src = wk; dst = wqkv + (1 << 20);  idx = b - 5120; }
    else if (b < 7168) { src = wv; dst = wqkv + (2 << 20);  idx = b - 6144; }
    else               { src = wo; dst = wob;               idx = b - 7168; }
    const int i = idx * 256 + threadIdx.x;
    floatx4 v = ((const floatx4*)src)[i];
    bf16x4 o;
    o.x = f2b(v.x); o.y = f2b(v.y); o.z = f2b(v.z); o.w = f2b(v.w);
    ((bf16x4*)dst)[i] = o;
}

// Fused QKV GEMM (m97 structure, 128x128 tile, BK=32). B rows: Wq|Wk|Wv.
// Q pre-scaled by 0.125*log2e (exp2-domain softmax). Q/K in [b,h,s,dh].
// ROUND-5 CHANGE: V written DIRECTLY transposed to vt [b,h,dh,s] — the 4
// consecutive-r acc values become 4 contiguous shorts there, so one bf16x4
// store per (i,j) (vs 4 stride-128B scatter stores). transpose_v kernel
// deleted. t (q/k/v) is block-uniform: 128-col tiles align to 1024 bounds.
__global__ __launch_bounds__(256) void gemm_qkv(const short* __restrict__ A,
        const short* __restrict__ B,
        const float* __restrict__ bq, const float* __restrict__ bk,
        const float* __restrict__ bv,
        short* __restrict__ qw, short* __restrict__ kw, short* __restrict__ vt)
{
    __shared__ short As[128 * 32];
    __shared__ short Bs[128 * 32];
    const int m0 = blockIdx.x * 128, n0 = blockIdx.y * 128;
    const int w = threadIdx.x >> 6, lane = threadIdx.x & 63;
    const int l16 = lane & 15, quad = lane >> 4;
    const int wm = w >> 1, wn = w & 1;
    const int lr = lane >> 2, lc = (lane & 3) * 8;

    floatx4 acc[4][4];
#pragma unroll
    for (int i = 0; i < 4; ++i)
#pragma unroll
        for (int j = 0; j < 4; ++j) acc[i][j] = (floatx4){0.f, 0.f, 0.f, 0.f};

    for (int kt = 0; kt < DM / 32; ++kt) {
        const int k0 = kt * 32;
        __syncthreads();
        async_copy16(A + (size_t)(m0 + w * 32 + lr) * DM + k0 + lc,      &As[w * 1024]);
        async_copy16(A + (size_t)(m0 + w * 32 + 16 + lr) * DM + k0 + lc, &As[w * 1024 + 512]);
        async_copy16(B + (size_t)(n0 + w * 32 + lr) * DM + k0 + lc,      &Bs[w * 1024]);
        async_copy16(B + (size_t)(n0 + w * 32 + 16 + lr) * DM + k0 + lc, &Bs[w * 1024 + 512]);
        __syncthreads();

        short8 af[4], bf[4];
#pragma unroll
        for (int i = 0; i < 4; ++i)
            af[i] = *(const short8*)&As[(wm * 64 + i * 16 + l16) * 32 + quad * 8];
#pragma unroll
        for (int j = 0; j < 4; ++j)
            bf[j] = *(const short8*)&Bs[(wn * 64 + j * 16 + l16) * 32 + quad * 8];
#pragma unroll
        for (int i = 0; i < 4; ++i)
#pragma unroll
            for (int j = 0; j < 4; ++j)
                acc[i][j] = __builtin_amdgcn_mfma_f32_16x16x32_bf16(af[i], bf[j], acc[i][j], 0, 0, 0);
    }

    const int m_base = m0 + wm * 64 + quad * 4;
    const int t = n0 >> 10;                  // block-uniform: q/k/v select
#pragma unroll
    for (int j = 0; j < 4; ++j) {
        const int nb = n0 + wn * 64 + j * 16;
        const int nn = (nb & 1023) + l16;
        const int h = nn >> 6, dh = nn & 63;
        if (t == 2) {                        // V -> vt [b,h,dh,s], vectorized
            const float bvv = bv[nn];
#pragma unroll
            for (int i = 0; i < 4; ++i) {
                const int m = m_base + i * 16;
                const int b = m >> 11, s = m & (SEQ - 1);
                bf16x4 o;
                o.x = f2b(acc[i][j][0] + bvv);
                o.y = f2b(acc[i][j][1] + bvv);
                o.z = f2b(acc[i][j][2] + bvv);
                o.w = f2b(acc[i][j][3] + bvv);
                *(bf16x4*)&vt[(((size_t)(b * HEADS + h)) * DH + dh) * SEQ + s] = o;
            }
        } else {                             // Q/K -> [b,h,s,dh] scatter
            const float* bias = (t == 0) ? bq : bk;
            short* dst = (t == 0) ? qw : kw;
            const float mulf = (t == 0) ? (0.125f * LOG2E) : 1.0f;
            const float bvv = bias[nn];
#pragma unroll
            for (int i = 0; i < 4; ++i)
#pragma unroll
                for (int r = 0; r < 4; ++r) {
                    const int m = m_base + i * 16 + r;
                    const int b = m >> 11, s = m & (SEQ - 1);
                    dst[(((size_t)(b * HEADS + h)) * SEQ + s) * DH + dh] =
                        f2b((acc[i][j][r] + bvv) * mulf);
                }
        }
    }
}

// Flash attention, 32x32x16 MFMA formulation.
// (R2-verified version: 71.0 µs, occ 33%, 4 blocks/CU. Reverted from the
// round-4 register-P experiment, which halved waves/CU -> 91.5 µs.)
// LDS arena cut to exactly 40960B so 4 blocks/CU fit.
//  - mask reads as GLOBAL floatx4 into VGPRs, issued BEFORE stage_kv
//    (sched_barrier pins order) so vmcnt(4) drains [prev copies + mask] and
//    keeps exactly the 4 new stage copies in flight.
//  - per-wave l_run accumulated privately; single cross-wave exchange in
//    epilogue via LDS aliased over retired K bufs.
// Arena: K2(16K) + V2(16K) + P(8K) = 40960B. Epilogue Ct+l_fin alias K bufs.
// Layouts: A/B 32x32x16: m(n)=lane&31, k=8*(lane>>5)+j. C/D: col=lane&31,
// row=(reg&3)+8*(reg>>2)+4*(lane>>5)  [m74/m101-verified].
__global__ __launch_bounds__(256) void attn_kernel(const short* __restrict__ q,
        const short* __restrict__ k, const short* __restrict__ vt,
        const float* __restrict__ maddg, short* __restrict__ ctx)
{
    const int id    = blockIdx.x;
    const int qtile = id >> 5;             // id = qtile*32 + bh
    const int bh    = id & 31;
    const int bidx  = bh >> 4;
    const int wave = threadIdx.x >> 6, lane = threadIdx.x & 63;
    const int l32 = lane & 31, half = lane >> 5;
    const int kw = wave & 1, qw = wave >> 1;   // S^T: keys kw*32.., qrows qw*32..
                                               // PV: dh kw*32.., qrows qw*32..

    // LDS arena (shorts), 20480 shorts = 40960 B exactly (4 blocks/CU):
    //  [    0.. 4096) k buf0   [ 4096.. 8192) k buf1
    //  [ 8192..12288) v buf0   [12288..16384) v buf1
    //  [16384..20480) p_lds
    //  epilogue (after loop, K bufs retired):
    //    Ct   = shorts [0..4608)
    //    l_fin= floats at short-offset 4608 (128 floats)
    __shared__ __align__(16) short smem[20480];
    short* p_lds = smem + 16384;
    short* Ct    = smem;
    float* l_fin = (float*)(smem + 4608);

    const short* kbase0 = k  + (size_t)bh * SEQ * DH;
    const short* vbase0 = vt + (size_t)bh * DH * SEQ;
    const float* mrow   = maddg + (size_t)bidx * SEQ;

    // Q B-frags: B[n=qrow=l32][k=dh = kk*16 + half*8 + j]
    const int qrow = qtile * 64 + qw * 32 + l32;
    const short* qbase = q + ((size_t)bh * SEQ + qrow) * DH;
    short8 b_q[4];
#pragma unroll
    for (int kk = 0; kk < 4; ++kk)
        b_q[kk] = *(const short8*)(qbase + kk * 16 + half * 8);

    floatx16 oacc;
#pragma unroll
    for (int r = 0; r < 16; ++r) oacc[r] = 0.f;
    float l_run = 0.f;

    // staging geometry: 512 chunks/tile, 256 threads -> 2 chunks/thread/array
    int srw[2], gg[2];
#pragma unroll
    for (int i = 0; i < 2; ++i) {
        const int slot = i * 256 + wave * 64 + lane;
        srw[i] = slot >> 3;
        gg[i]  = (slot & 7) ^ (srw[i] & 7);
    }

    const int prow = qw * 32 + l32;        // this lane's qrow (local 0..63)

    // stage K/V tile kt into buffer buf (4 copies/thread: K,V,K,V)
    auto stage_kv = [&](int buf, int kt) {
        const short* kbase = kbase0 + (size_t)(kt * 64) * DH;
        const short* vbase = vbase0 + kt * 64;
        const int ko = buf << 12;
        const int vo = 8192 + (buf << 12);
#pragma unroll
        for (int i = 0; i < 2; ++i) {
            async_copy16(kbase + srw[i] * DH + gg[i] * 8,
                         &smem[ko + (i * 256 + wave * 64) * 8]);
            async_copy16(vbase + (size_t)srw[i] * SEQ + gg[i] * 8,
                         &smem[vo + (i * 256 + wave * 64) * 8]);
        }
    };

    // prologue: tile 0 into buf 0 (drained by iter-0's vmcnt(4)).
    stage_kv(0, 0);

    int cur = 0;
    for (int kt = 0; kt < SEQ / 64; ++kt) {
        // B1: prev-iter reads of buf[cur^1] / p_lds are complete
        asm volatile("" ::: "memory");
        __builtin_amdgcn_s_barrier();

        // mask C-init loads (global, VGPR): issued BEFORE staging so the
        // counted vmcnt(4) below drains them together with prev-tile copies.
        floatx4 md[4];
#pragma unroll
        for (int g = 0; g < 4; ++g)
            md[g] = *(const floatx4*)&mrow[kt * 64 + kw * 32 + 8 * g + 4 * half];
        __builtin_amdgcn_sched_barrier(0);   // pin: md loads before stage copies

        if (kt + 1 < SEQ / 64) {
            stage_kv(cur ^ 1, kt + 1);
            // drain everything except the 4 copies just issued
            asm volatile("s_waitcnt vmcnt(4)" ::: "memory");
        } else {
            asm volatile("s_waitcnt vmcnt(0)" ::: "memory");
        }
        __builtin_amdgcn_s_barrier();      // B2: buf[cur] + md landed

        // S^T = K Q^T (log2 domain), 4 MFMA 32x32x16, C init = mask
        floatx16 s;
#pragma unroll
        for (int g = 0; g < 4; ++g)
#pragma unroll
            for (int r = 0; r < 4; ++r) s[g * 4 + r] = md[g][r];
        {
            const int ko = cur << 12;
            const int krow = kw * 32 + l32;
            const int ksw = krow & 7;
#pragma unroll
            for (int kk = 0; kk < 4; ++kk) {
                const int c = kk * 2 + half;
                short8 a = *(const short8*)&smem[ko + krow * 64 + ((c ^ ksw) * 8)];
                s = __builtin_amdgcn_mfma_f32_32x32x16_bf16(a, b_q[kk], s, 0, 0, 0);
            }
        }

        // p = exp2(min(s,40)); private row-sum; packed stores to p_lds [qrow][key]
        float lsum = 0.f;
        const int psw = prow & 7;
#pragma unroll
        for (int g = 0; g < 4; ++g) {
            const float p0 = fexp2(fminf(s[g * 4 + 0], 40.f));
            const float p1 = fexp2(fminf(s[g * 4 + 1], 40.f));
            const float p2 = fexp2(fminf(s[g * 4 + 2], 40.f));
            const float p3 = fexp2(fminf(s[g * 4 + 3], 40.f));
            lsum += (p0 + p1) + (p2 + p3);
            union { __hip_bfloat162 h[2]; bf16x4 v; } u;
            u.h[0] = __float22bfloat162_rn(make_float2(p0, p1));
            u.h[1] = __float22bfloat162_rn(make_float2(p2, p3));
            const int c = kw * 4 + g;      // chunk of key offset kw*32+8g
            *(bf16x4*)&p_lds[prow * 64 + ((c ^ psw) * 8) + 4 * half] = u.v;
        }
        l_run += lsum;                     // deferred cross-wave combine

        // B3: P visible (lgkm only — do NOT drain the prefetch)
        asm volatile("s_waitcnt lgkmcnt(0)" ::: "memory");
        __builtin_amdgcn_s_barrier();

        // O^T += V^T P^T : A=V^T[dh][key], B=P[qrow][key], 4 MFMA 32x32x16
        {
            const int vo = 8192 + (cur << 12);
            const int vrow = kw * 32 + l32;    // dh row
            const int vsw = vrow & 7;
#pragma unroll
            for (int kk = 0; kk < 4; ++kk) {
                const int c = kk * 2 + half;
                short8 av = *(const short8*)&smem[vo + vrow * 64 + ((c ^ vsw) * 8)];
                short8 bp = *(const short8*)&p_lds[prow * 64 + ((c ^ psw) * 8)];
                oacc = __builtin_amdgcn_mfma_f32_32x32x16_bf16(av, bp, oacc, 0, 0, 0);
            }
        }
        cur ^= 1;
    }

    // E1: loop fully done; K-buffer region retires for Ct/l_fin reuse
    asm volatile("" ::: "memory");
    __builtin_amdgcn_s_barrier();

    // cross-half + cross-wave l combine (once): halves share qrow via shfl,
    // kw-pair shares via LDS.
    const float l_mine = l_run + __shfl_xor(l_run, 32);
    l_fin[kw * 64 + prow] = l_mine;        // dup write from both halves, same value
    asm volatile("s_waitcnt lgkmcnt(0)" ::: "memory");
    __builtin_amdgcn_s_barrier();          // E2: l_fin visible

    // epilogue: O^T[dh][qrow] / l -> Ct[qrow][dh] -> coalesced global stores
    const int h = bh & 15, bb = bh >> 4;
    const float rl = 1.f / (l_fin[prow] + l_fin[64 + prow]);
#pragma unroll
    for (int g = 0; g < 4; ++g) {
        bf16x4 p;
        p.x = f2b(oacc[g * 4 + 0] * rl);
        p.y = f2b(oacc[g * 4 + 1] * rl);
        p.z = f2b(oacc[g * 4 + 2] * rl);
        p.w = f2b(oacc[g * 4 + 3] * rl);
        const int dh = kw * 32 + 8 * g + 4 * half;   // row=(reg&3)+8g+4*half
        *(bf16x4*)&Ct[prow * 72 + dh] = p;
    }
    __syncthreads();                       // E3
    {
        const int row = threadIdx.x >> 2, ch = threadIdx.x & 3;
        short8 v0 = *(const short8*)&Ct[row * 72 + ch * 16];
        short8 v1 = *(const short8*)&Ct[row * 72 + ch * 16 + 8];
        short* gp = ctx + ((size_t)(bb * SEQ + qtile * 64 + row)) * DM + h * 64 + ch * 16;
        *(short8*)gp = v0;
        *(short8*)(gp + 8) = v1;
    }
}

// Output GEMM + bias + residual (fp32 out into d_out). 128x64 tile, 2 blocks/CU.
__global__ __launch_bounds__(256) void gemm_o(const short* __restrict__ A,
        const short* __restrict__ B, const float* __restrict__ bo,
        const float* __restrict__ xin, float* __restrict__ out)
{
    __shared__ short As[128 * 32];
    __shared__ short Bs[64 * 32];
    const int m0 = blockIdx.x * 128, n0 = blockIdx.y * 64;
    const int w = threadIdx.x >> 6, lane = threadIdx.x & 63;
    const int l16 = lane & 15, quad = lane >> 4;
    const int wm = w >> 1, wn = w & 1;     // wave: 64 rows x 32 cols

    floatx4 acc[4][2];
#pragma unroll
    for (int i = 0; i < 4; ++i)
#pragma unroll
        for (int j = 0; j < 2; ++j) acc[i][j] = (floatx4){0.f, 0.f, 0.f, 0.f};

    const int c0 = w * 64 + lane;

    for (int kt = 0; kt < DM / 32; ++kt) {
        const int k0 = kt * 32;
        __syncthreads();
        {
            const int ra0 = c0 >> 2,          ca0 = (c0 & 3) * 8;
            const int ra1 = (256 + c0) >> 2,  ca1 = (c0 & 3) * 8;
            async_copy16(A + (size_t)(m0 + ra0) * DM + k0 + ca0, &As[(w * 64) * 8]);
            async_copy16(A + (size_t)(m0 + ra1) * DM + k0 + ca1, &As[(256 + w * 64) * 8]);
            const int rb = c0 >> 2, cb = (c0 & 3) * 8;
            async_copy16(B + (size_t)(n0 + rb) * DM + k0 + cb,   &Bs[(w * 64) * 8]);
        }
        __syncthreads();

        short8 af[4], bf[2];
#pragma unroll
        for (int i = 0; i < 4; ++i)
            af[i] = *(const short8*)&As[(wm * 64 + i * 16 + l16) * 32 + quad * 8];
#pragma unroll
        for (int j = 0; j < 2; ++j)
            bf[j] = *(const short8*)&Bs[(wn * 32 + j * 16 + l16) * 32 + quad * 8];
#pragma unroll
        for (int i = 0; i < 4; ++i)
#pragma unroll
            for (int j = 0; j < 2; ++j)
                acc[i][j] = __builtin_amdgcn_mfma_f32_16x16x32_bf16(af[i], bf[j], acc[i][j], 0, 0, 0);
    }

    const int m_base = m0 + wm * 64 + quad * 4;
#pragma unroll
    for (int j = 0; j < 2; ++j) {
        const int n = n0 + wn * 32 + j * 16 + l16;
        const float bvv = bo[n];
#pragma unroll
        for (int i = 0; i < 4; ++i)
#pragma unroll
            for (int r = 0; r < 4; ++r) {
                const int m = m_base + i * 16 + r;
                const size_t idx = (size_t)m * DM + n;
                out[idx] = acc[i][j][r] + bvv + xin[idx];
            }
    }
}

__global__ __launch_bounds__(256) void ln_kernel(float* __restrict__ y,
        const float* __restrict__ gamma, const float* __restrict__ beta)
{
    const int row = blockIdx.x;
    const int t = threadIdx.x;
    const int wave = t >> 6, lane = t & 63;
    const floatx4 v = ((const floatx4*)(y + (size_t)row * DM))[t];
    float s  = v.x + v.y + v.z + v.w;
    float q2 = v.x * v.x + v.y * v.y + v.z * v.z + v.w * v.w;
#pragma unroll
    for (int off = 1; off < 64; off <<= 1) {
        s  += __shfl_xor(s, off);
        q2 += __shfl_xor(q2, off);
    }
    __shared__ float rs[4], rq[4];
    if (lane == 0) { rs[wave] = s; rq[wave] = q2; }
    __syncthreads();
    const float S  = rs[0] + rs[1] + rs[2] + rs[3];
    const float Q2 = rq[0] + rq[1] + rq[2] + rq[3];
    const float mu = S * (1.f / DM);
    float var = Q2 * (1.f / DM) - mu * mu;
    var = fmaxf(var, 0.f);
    const float rstd = rsqrtf(var + 1e-12f);
    const floatx4 g = ((const floatx4*)gamma)[t];
    const floatx4 bt = ((const floatx4*)beta)[t];
    floatx4 o;
    o.x = (v.x - mu) * rstd * g.x + bt.x;
    o.y = (v.y - mu) * rstd * g.y + bt.y;
    o.z = (v.z - mu) * rstd * g.z + bt.z;
    o.w = (v.w - mu) * rstd * g.w + bt.w;
    ((floatx4*)(y + (size_t)row * DM))[t] = o;
}

extern "C" void kernel_launch(void* const* d_in, const int* in_sizes, int n_in,
                              void* d_out, int out_size, void* d_ws, size_t ws_size,
                              hipStream_t stream) {
    const float* x     = (const float*)d_in[0];
    const float* mask  = (const float*)d_in[1];
    const float* Wq    = (const float*)d_in[2];
    const float* bq    = (const float*)d_in[3];
    const float* Wk    = (const float*)d_in[4];
    const float* bk    = (const float*)d_in[5];
    const float* Wv    = (const float*)d_in[6];
    const float* bv    = (const float*)d_in[7];
    const float* Wo    = (const float*)d_in[8];
    const float* bo    = (const float*)d_in[9];
    const float* gamma = (const float*)d_in[10];
    const float* beta  = (const float*)d_in[11];
    float* out = (float*)d_out;

    const size_t NTOK = (size_t)BATCH * SEQ * DM;       // 4M
    const size_t WSZ  = (size_t)DM * DM;                // 1M
    short* xb   = (short*)d_ws;          // 4M shorts
    short* wqkv = xb + NTOK;             // 3M
    short* wob  = wqkv + 3 * WSZ;        // 1M
    short* qw   = wob + WSZ;             // 4M
    short* kw   = qw + NTOK;             // 4M
    short* vw   = kw + NTOK;             // 4M (free; aliased as ctx)
    short* vtw  = vw + NTOK;             // 4M (V written transposed by gemm_qkv)
    short* ctxw = vw;
    float* maddg = (float*)(vtw + NTOK); // 4096 floats

    dim3 blk(256);
    cvt_all<<<dim3(8194), blk, 0, stream>>>(x, Wq, Wk, Wv, Wo, mask, xb, wqkv, wob, maddg);
    gemm_qkv<<<dim3(32, 24), blk, 0, stream>>>(xb, wqkv, bq, bk, bv, qw, kw, vtw);
    attn_kernel<<<dim3(32 * 32), blk, 0, stream>>>(qw, kw, vtw, maddg, ctxw);
    gemm_o<<<dim3(32, 16), blk, 0, stream>>>(ctxw, wob, bo, x, out);
    ln_kernel<<<BATCH * SEQ, blk, 0, stream>>>(out, gamma, beta);
}

// Round 8
// 229.731 us; speedup vs baseline: 1.0357x; 1.0036x over previous
//
#include <hip/hip_runtime.h>
#include <hip/hip_bf16.h>

#define DM   1024
#define HEADS 16
#define DH    64
#define SEQ  2048
#define BATCH   2
#define LOG2E 1.44269504088896f

typedef __attribute__((ext_vector_type(8))) short short8;
typedef __attribute__((ext_vector_type(4))) short bf16x4;
typedef __attribute__((ext_vector_type(4))) float floatx4;
typedef __attribute__((ext_vector_type(16))) float floatx16;

__device__ __forceinline__ short f2b(float f) {
    union { float f; unsigned u; } v; v.f = f;
    unsigned r = v.u + 0x7FFFu + ((v.u >> 16) & 1u);
    return (short)(r >> 16);
}

#if __has_builtin(__builtin_amdgcn_exp2f)
__device__ __forceinline__ float fexp2(float x) { return __builtin_amdgcn_exp2f(x); }
#else
__device__ __forceinline__ float fexp2(float x) { return exp2f(x); }
#endif

__device__ __forceinline__ void async_copy16(const short* gsrc, short* ldst) {
    __builtin_amdgcn_global_load_lds(
        (const __attribute__((address_space(1))) void*)gsrc,
        (__attribute__((address_space(3))) void*)ldst,
        16, 0, 0);
}

// Fused fp32->bf16 conversion of x, Wq, Wk, Wv, Wo + mask-add table (log2 domain).
__global__ __launch_bounds__(256) void cvt_all(const float* __restrict__ x,
        const float* __restrict__ wq, const float* __restrict__ wk,
        const float* __restrict__ wv, const float* __restrict__ wo,
        const float* __restrict__ mask,
        short* __restrict__ xb, short* __restrict__ wqkv, short* __restrict__ wob,
        float* __restrict__ maddg)
{
    const int b = blockIdx.x;
    if (b >= 8192) {            // mask prep: maddg = (1-mask) * (-1e5 * log2e)
        const int bb = b - 8192;
        const float* mrow = mask + (size_t)bb * SEQ;
        float* mg = maddg + (size_t)bb * SEQ;
#pragma unroll
        for (int i = 0; i < 8; ++i) {
            const int idx = threadIdx.x * 8 + i;
            mg[idx] = (1.f - mrow[idx]) * (-100000.f * LOG2E);
        }
        return;
    }
    const float* src; short* dst; int idx;
    if (b < 4096)      { src = x;  dst = xb;                idx = b; }
    else if (b < 5120) { src = wq; dst = wqkv;              idx = b - 4096; }
    else if (b < 6144) { src = wk; dst = wqkv + (1 << 20);  idx = b - 5120; }
    else if (b < 7168) { src = wv; dst = wqkv + (2 << 20);  idx = b - 6144; }
    else               { src = wo; dst = wob;               idx = b - 7168; }
    const int i = idx * 256 + threadIdx.x;
    floatx4 v = ((const floatx4*)src)[i];
    bf16x4 o;
    o.x = f2b(v.x); o.y = f2b(v.y); o.z = f2b(v.z); o.w = f2b(v.w);
    ((bf16x4*)dst)[i] = o;
}

// Fused QKV GEMM (m97 structure, 128x128 tile, BK=32). B rows: Wq|Wk|Wv.
// Q pre-scaled by 0.125*log2e (exp2-domain softmax). Q/K in [b,h,s,dh].
// V written DIRECTLY transposed to vt [b,h,dh,s] (4 consecutive-r acc values
// are contiguous there -> one bf16x4 store). transpose_v kernel deleted.
__global__ __launch_bounds__(256) void gemm_qkv(const short* __restrict__ A,
        const short* __restrict__ B,
        const float* __restrict__ bq, const float* __restrict__ bk,
        const float* __restrict__ bv,
        short* __restrict__ qw, short* __restrict__ kw, short* __restrict__ vt)
{
    __shared__ short As[128 * 32];
    __shared__ short Bs[128 * 32];
    const int m0 = blockIdx.x * 128, n0 = blockIdx.y * 128;
    const int w = threadIdx.x >> 6, lane = threadIdx.x & 63;
    const int l16 = lane & 15, quad = lane >> 4;
    const int wm = w >> 1, wn = w & 1;
    const int lr = lane >> 2, lc = (lane & 3) * 8;

    floatx4 acc[4][4];
#pragma unroll
    for (int i = 0; i < 4; ++i)
#pragma unroll
        for (int j = 0; j < 4; ++j) acc[i][j] = (floatx4){0.f, 0.f, 0.f, 0.f};

    for (int kt = 0; kt < DM / 32; ++kt) {
        const int k0 = kt * 32;
        __syncthreads();
        async_copy16(A + (size_t)(m0 + w * 32 + lr) * DM + k0 + lc,      &As[w * 1024]);
        async_copy16(A + (size_t)(m0 + w * 32 + 16 + lr) * DM + k0 + lc, &As[w * 1024 + 512]);
        async_copy16(B + (size_t)(n0 + w * 32 + lr) * DM + k0 + lc,      &Bs[w * 1024]);
        async_copy16(B + (size_t)(n0 + w * 32 + 16 + lr) * DM + k0 + lc, &Bs[w * 1024 + 512]);
        __syncthreads();

        short8 af[4], bf[4];
#pragma unroll
        for (int i = 0; i < 4; ++i)
            af[i] = *(const short8*)&As[(wm * 64 + i * 16 + l16) * 32 + quad * 8];
#pragma unroll
        for (int j = 0; j < 4; ++j)
            bf[j] = *(const short8*)&Bs[(wn * 64 + j * 16 + l16) * 32 + quad * 8];
#pragma unroll
        for (int i = 0; i < 4; ++i)
#pragma unroll
            for (int j = 0; j < 4; ++j)
                acc[i][j] = __builtin_amdgcn_mfma_f32_16x16x32_bf16(af[i], bf[j], acc[i][j], 0, 0, 0);
    }

    const int m_base = m0 + wm * 64 + quad * 4;
    const int t = n0 >> 10;                  // block-uniform: q/k/v select
#pragma unroll
    for (int j = 0; j < 4; ++j) {
        const int nb = n0 + wn * 64 + j * 16;
        const int nn = (nb & 1023) + l16;
        const int h = nn >> 6, dh = nn & 63;
        if (t == 2) {                        // V -> vt [b,h,dh,s], vectorized
            const float bvv = bv[nn];
#pragma unroll
            for (int i = 0; i < 4; ++i) {
                const int m = m_base + i * 16;
                const int b = m >> 11, s = m & (SEQ - 1);
                bf16x4 o;
                o.x = f2b(acc[i][j][0] + bvv);
                o.y = f2b(acc[i][j][1] + bvv);
                o.z = f2b(acc[i][j][2] + bvv);
                o.w = f2b(acc[i][j][3] + bvv);
                *(bf16x4*)&vt[(((size_t)(b * HEADS + h)) * DH + dh) * SEQ + s] = o;
            }
        } else {                             // Q/K -> [b,h,s,dh] scatter
            const float* bias = (t == 0) ? bq : bk;
            short* dst = (t == 0) ? qw : kw;
            const float mulf = (t == 0) ? (0.125f * LOG2E) : 1.0f;
            const float bvv = bias[nn];
#pragma unroll
            for (int i = 0; i < 4; ++i)
#pragma unroll
                for (int r = 0; r < 4; ++r) {
                    const int m = m_base + i * 16 + r;
                    const int b = m >> 11, s = m & (SEQ - 1);
                    dst[(((size_t)(b * HEADS + h)) * SEQ + s) * DH + dh] =
                        f2b((acc[i][j][r] + bvv) * mulf);
                }
        }
    }
}

// Flash attention, 32x32x16 MFMA formulation.
// ROUND-6 CHANGE (resubmitted round-7; R6 bench lost to GPU-broker timeout):
// single-buffered V -> LDS 32768B (5 blocks/CU capacity, slack
// for the dispatcher; was 40960B = 4 exact, measured occ only 33%).
// Per-iter FIFO: issue md(4) -> V(kt)(2) -> K(kt+1)(2); invariant: K(kt)x2
// outstanding entering iter kt.
//   before S^T: vmcnt(4)  (drain K(kt)+md; keep V(kt)+K(kt+1))  + barrier B2
//   before PV : lgkmcnt(0) + vmcnt(2) (drain V(kt); keep K(kt+1)) + barrier B3
// Last iter: vmcnt(2) / vmcnt(0). B1 guarantees vbuf reads of iter kt-1 are
// consumed before re-staging.
// Arena: K2(16K) + V(8K) + P(8K) = 32768B. Epilogue Ct+l_fin alias K bufs.
// Layouts: A/B 32x32x16: m(n)=lane&31, k=8*(lane>>5)+j. C/D: col=lane&31,
// row=(reg&3)+8*(reg>>2)+4*(lane>>5)  [m74/m101-verified].
__global__ __launch_bounds__(256) void attn_kernel(const short* __restrict__ q,
        const short* __restrict__ k, const short* __restrict__ vt,
        const float* __restrict__ maddg, short* __restrict__ ctx)
{
    const int id    = blockIdx.x;
    const int qtile = id >> 5;             // id = qtile*32 + bh
    const int bh    = id & 31;
    const int bidx  = bh >> 4;
    const int wave = threadIdx.x >> 6, lane = threadIdx.x & 63;
    const int l32 = lane & 31, half = lane >> 5;
    const int kw = wave & 1, qw = wave >> 1;   // S^T: keys kw*32.., qrows qw*32..
                                               // PV: dh kw*32.., qrows qw*32..

    // LDS arena (shorts), 16384 shorts = 32768 B:
    //  [    0.. 4096) k buf0   [ 4096.. 8192) k buf1
    //  [ 8192..12288) v buf (single)
    //  [12288..16384) p_lds
    //  epilogue (K bufs retired): Ct = shorts [0..4608),
    //                             l_fin = floats at short-offset 4608
    __shared__ __align__(16) short smem[16384];
    short* p_lds = smem + 12288;
    short* Ct    = smem;
    float* l_fin = (float*)(smem + 4608);

    const short* kbase0 = k  + (size_t)bh * SEQ * DH;
    const short* vbase0 = vt + (size_t)bh * DH * SEQ;
    const float* mrow   = maddg + (size_t)bidx * SEQ;

    // Q B-frags: B[n=qrow=l32][k=dh = kk*16 + half*8 + j]
    const int qrow = qtile * 64 + qw * 32 + l32;
    const short* qbase = q + ((size_t)bh * SEQ + qrow) * DH;
    short8 b_q[4];
#pragma unroll
    for (int kk = 0; kk < 4; ++kk)
        b_q[kk] = *(const short8*)(qbase + kk * 16 + half * 8);

    floatx16 oacc;
#pragma unroll
    for (int r = 0; r < 16; ++r) oacc[r] = 0.f;
    float l_run = 0.f;

    // staging geometry: 512 chunks/tile, 256 threads -> 2 chunks/thread/array
    int srw[2], gg[2];
#pragma unroll
    for (int i = 0; i < 2; ++i) {
        const int slot = i * 256 + wave * 64 + lane;
        srw[i] = slot >> 3;
        gg[i]  = (slot & 7) ^ (srw[i] & 7);
    }

    const int prow = qw * 32 + l32;        // this lane's qrow (local 0..63)

    auto stage_k = [&](int buf, int kt) {
        const short* kbase = kbase0 + (size_t)(kt * 64) * DH;
        const int ko = buf << 12;
#pragma unroll
        for (int i = 0; i < 2; ++i)
            async_copy16(kbase + srw[i] * DH + gg[i] * 8,
                         &smem[ko + (i * 256 + wave * 64) * 8]);
    };
    auto stage_v = [&](int kt) {
        const short* vbase = vbase0 + kt * 64;
#pragma unroll
        for (int i = 0; i < 2; ++i)
            async_copy16(vbase + (size_t)srw[i] * SEQ + gg[i] * 8,
                         &smem[8192 + (i * 256 + wave * 64) * 8]);
    };

    // prologue: K tile 0 into buf 0 (drained by iter-0's vmcnt(4)).
    stage_k(0, 0);

    int cur = 0;
    for (int kt = 0; kt < SEQ / 64; ++kt) {
        // B1: prev-iter reads of vbuf / p_lds complete; kbuf[cur^1] retired
        asm volatile("" ::: "memory");
        __builtin_amdgcn_s_barrier();

        // FIFO: md(4) -> V(kt)(2) -> K(kt+1)(2)
        floatx4 md[4];
#pragma unroll
        for (int g = 0; g < 4; ++g)
            md[g] = *(const floatx4*)&mrow[kt * 64 + kw * 32 + 8 * g + 4 * half];
        __builtin_amdgcn_sched_barrier(0);   // pin: md before V staging
        stage_v(kt);
        __builtin_amdgcn_sched_barrier(0);   // pin: V before K staging
        const bool has_next = (kt + 1 < SEQ / 64);
        if (has_next) {
            stage_k(cur ^ 1, kt + 1);
            // drain K(kt)+md; keep V(kt)x2 + K(kt+1)x2 in flight
            asm volatile("s_waitcnt vmcnt(4)" ::: "memory");
        } else {
            // drain K(kt)+md; keep V(kt)x2
            asm volatile("s_waitcnt vmcnt(2)" ::: "memory");
        }
        __builtin_amdgcn_s_barrier();      // B2: kbuf[cur] + md landed (all waves)

        // S^T = K Q^T (log2 domain), 4 MFMA 32x32x16, C init = mask
        floatx16 s;
#pragma unroll
        for (int g = 0; g < 4; ++g)
#pragma unroll
            for (int r = 0; r < 4; ++r) s[g * 4 + r] = md[g][r];
        {
            const int ko = cur << 12;
            const int krow = kw * 32 + l32;
            const int ksw = krow & 7;
#pragma unroll
            for (int kk = 0; kk < 4; ++kk) {
                const int c = kk * 2 + half;
                short8 a = *(const short8*)&smem[ko + krow * 64 + ((c ^ ksw) * 8)];
                s = __builtin_amdgcn_mfma_f32_32x32x16_bf16(a, b_q[kk], s, 0, 0, 0);
            }
        }

        // p = exp2(min(s,40)); private row-sum; packed stores to p_lds [qrow][key]
        float lsum = 0.f;
        const int psw = prow & 7;
#pragma unroll
        for (int g = 0; g < 4; ++g) {
            const float p0 = fexp2(fminf(s[g * 4 + 0], 40.f));
            const float p1 = fexp2(fminf(s[g * 4 + 1], 40.f));
            const float p2 = fexp2(fminf(s[g * 4 + 2], 40.f));
            const float p3 = fexp2(fminf(s[g * 4 + 3], 40.f));
            lsum += (p0 + p1) + (p2 + p3);
            union { __hip_bfloat162 h[2]; bf16x4 v; } u;
            u.h[0] = __float22bfloat162_rn(make_float2(p0, p1));
            u.h[1] = __float22bfloat162_rn(make_float2(p2, p3));
            const int c = kw * 4 + g;      // chunk of key offset kw*32+8g
            *(bf16x4*)&p_lds[prow * 64 + ((c ^ psw) * 8) + 4 * half] = u.v;
        }
        l_run += lsum;                     // deferred cross-wave combine

        // B3: P visible + V(kt) landed (keep K(kt+1) prefetch in flight)
        asm volatile("s_waitcnt lgkmcnt(0)" ::: "memory");
        if (has_next) {
            asm volatile("s_waitcnt vmcnt(2)" ::: "memory");
        } else {
            asm volatile("s_waitcnt vmcnt(0)" ::: "memory");
        }
        __builtin_amdgcn_s_barrier();

        // O^T += V^T P^T : A=V^T[dh][key], B=P[qrow][key], 4 MFMA 32x32x16
        {
            const int vrow = kw * 32 + l32;    // dh row
            const int vsw = vrow & 7;
#pragma unroll
            for (int kk = 0; kk < 4; ++kk) {
                const int c = kk * 2 + half;
                short8 av = *(const short8*)&smem[8192 + vrow * 64 + ((c ^ vsw) * 8)];
                short8 bp = *(const short8*)&p_lds[prow * 64 + ((c ^ psw) * 8)];
                oacc = __builtin_amdgcn_mfma_f32_32x32x16_bf16(av, bp, oacc, 0, 0, 0);
            }
        }
        cur ^= 1;
    }

    // E1: loop fully done; K-buffer region retires for Ct/l_fin reuse
    asm volatile("" ::: "memory");
    __builtin_amdgcn_s_barrier();

    // cross-half + cross-wave l combine (once): halves share qrow via shfl,
    // kw-pair shares via LDS.
    const float l_mine = l_run + __shfl_xor(l_run, 32);
    l_fin[kw * 64 + prow] = l_mine;        // dup write from both halves, same value
    asm volatile("s_waitcnt lgkmcnt(0)" ::: "memory");
    __builtin_amdgcn_s_barrier();          // E2: l_fin visible

    // epilogue: O^T[dh][qrow] / l -> Ct[qrow][dh] -> coalesced global stores
    const int h = bh & 15, bb = bh >> 4;
    const float rl = 1.f / (l_fin[prow] + l_fin[64 + prow]);
#pragma unroll
    for (int g = 0; g < 4; ++g) {
        bf16x4 p;
        p.x = f2b(oacc[g * 4 + 0] * rl);
        p.y = f2b(oacc[g * 4 + 1] * rl);
        p.z = f2b(oacc[g * 4 + 2] * rl);
        p.w = f2b(oacc[g * 4 + 3] * rl);
        const int dh = kw * 32 + 8 * g + 4 * half;   // row=(reg&3)+8g+4*half
        *(bf16x4*)&Ct[prow * 72 + dh] = p;
    }
    __syncthreads();                       // E3
    {
        const int row = threadIdx.x >> 2, ch = threadIdx.x & 3;
        short8 v0 = *(const short8*)&Ct[row * 72 + ch * 16];
        short8 v1 = *(const short8*)&Ct[row * 72 + ch * 16 + 8];
        short* gp = ctx + ((size_t)(bb * SEQ + qtile * 64 + row)) * DM + h * 64 + ch * 16;
        *(short8*)gp = v0;
        *(short8*)(gp + 8) = v1;
    }
}

// Output GEMM + bias + residual (fp32 out into d_out). 128x64 tile, 2 blocks/CU.
__global__ __launch_bounds__(256) void gemm_o(const short* __restrict__ A,
        const short* __restrict__ B, const float* __restrict__ bo,
        const float* __restrict__ xin, float* __restrict__ out)
{
    __shared__ short As[128 * 32];
    __shared__ short Bs[64 * 32];
    const int m0 = blockIdx.x * 128, n0 = blockIdx.y * 64;
    const int w = threadIdx.x >> 6, lane = threadIdx.x & 63;
    const int l16 = lane & 15, quad = lane >> 4;
    const int wm = w >> 1, wn = w & 1;     // wave: 64 rows x 32 cols

    floatx4 acc[4][2];
#pragma unroll
    for (int i = 0; i < 4; ++i)
#pragma unroll
        for (int j = 0; j < 2; ++j) acc[i][j] = (floatx4){0.f, 0.f, 0.f, 0.f};

    const int c0 = w * 64 + lane;

    for (int kt = 0; kt < DM / 32; ++kt) {
        const int k0 = kt * 32;
        __syncthreads();
        {
            const int ra0 = c0 >> 2,          ca0 = (c0 & 3) * 8;
            const int ra1 = (256 + c0) >> 2,  ca1 = (c0 & 3) * 8;
            async_copy16(A + (size_t)(m0 + ra0) * DM + k0 + ca0, &As[(w * 64) * 8]);
            async_copy16(A + (size_t)(m0 + ra1) * DM + k0 + ca1, &As[(256 + w * 64) * 8]);
            const int rb = c0 >> 2, cb = (c0 & 3) * 8;
            async_copy16(B + (size_t)(n0 + rb) * DM + k0 + cb,   &Bs[(w * 64) * 8]);
        }
        __syncthreads();

        short8 af[4], bf[2];
#pragma unroll
        for (int i = 0; i < 4; ++i)
            af[i] = *(const short8*)&As[(wm * 64 + i * 16 + l16) * 32 + quad * 8];
#pragma unroll
        for (int j = 0; j < 2; ++j)
            bf[j] = *(const short8*)&Bs[(wn * 32 + j * 16 + l16) * 32 + quad * 8];
#pragma unroll
        for (int i = 0; i < 4; ++i)
#pragma unroll
            for (int j = 0; j < 2; ++j)
                acc[i][j] = __builtin_amdgcn_mfma_f32_16x16x32_bf16(af[i], bf[j], acc[i][j], 0, 0, 0);
    }

    const int m_base = m0 + wm * 64 + quad * 4;
#pragma unroll
    for (int j = 0; j < 2; ++j) {
        const int n = n0 + wn * 32 + j * 16 + l16;
        const float bvv = bo[n];
#pragma unroll
        for (int i = 0; i < 4; ++i)
#pragma unroll
            for (int r = 0; r < 4; ++r) {
                const int m = m_base + i * 16 + r;
                const size_t idx = (size_t)m * DM + n;
                out[idx] = acc[i][j][r] + bvv + xin[idx];
            }
    }
}

__global__ __launch_bounds__(256) void ln_kernel(float* __restrict__ y,
        const float* __restrict__ gamma, const float* __restrict__ beta)
{
    const int row = blockIdx.x;
    const int t = threadIdx.x;
    const int wave = t >> 6, lane = t & 63;
    const floatx4 v = ((const floatx4*)(y + (size_t)row * DM))[t];
    float s  = v.x + v.y + v.z + v.w;
    float q2 = v.x * v.x + v.y * v.y + v.z * v.z + v.w * v.w;
#pragma unroll
    for (int off = 1; off < 64; off <<= 1) {
        s  += __shfl_xor(s, off);
        q2 += __shfl_xor(q2, off);
    }
    __shared__ float rs[4], rq[4];
    if (lane == 0) { rs[wave] = s; rq[wave] = q2; }
    __syncthreads();
    const float S  = rs[0] + rs[1] + rs[2] + rs[3];
    const float Q2 = rq[0] + rq[1] + rq[2] + rq[3];
    const float mu = S * (1.f / DM);
    float var = Q2 * (1.f / DM) - mu * mu;
    var = fmaxf(var, 0.f);
    const float rstd = rsqrtf(var + 1e-12f);
    const floatx4 g = ((const floatx4*)gamma)[t];
    const floatx4 bt = ((const floatx4*)beta)[t];
    floatx4 o;
    o.x = (v.x - mu) * rstd * g.x + bt.x;
    o.y = (v.y - mu) * rstd * g.y + bt.y;
    o.z = (v.z - mu) * rstd * g.z + bt.z;
    o.w = (v.w - mu) * rstd * g.w + bt.w;
    ((floatx4*)(y + (size_t)row * DM))[t] = o;
}

extern "C" void kernel_launch(void* const* d_in, const int* in_sizes, int n_in,
                              void* d_out, int out_size, void* d_ws, size_t ws_size,
                              hipStream_t stream) {
    const float* x     = (const float*)d_in[0];
    const float* mask  = (const float*)d_in[1];
    const float* Wq    = (const float*)d_in[2];
    const float* bq    = (const float*)d_in[3];
    const float* Wk    = (const float*)d_in[4];
    const float* bk    = (const float*)d_in[5];
    const float* Wv    = (const float*)d_in[6];
    const float* bv    = (const float*)d_in[7];
    const float* Wo    = (const float*)d_in[8];
    const float* bo    = (const float*)d_in[9];
    const float* gamma = (const float*)d_in[10];
    const float* beta  = (const float*)d_in[11];
    float* out = (float*)d_out;

    const size_t NTOK = (size_t)BATCH * SEQ * DM;       // 4M
    const size_t WSZ  = (size_t)DM * DM;                // 1M
    short* xb   = (short*)d_ws;          // 4M shorts
    short* wqkv = xb + NTOK;             // 3M
    short* wob  = wqkv + 3 * WSZ;        // 1M
    short* qw   = wob + WSZ;             // 4M
    short* kw   = qw + NTOK;             // 4M
    short* vw   = kw + NTOK;             // 4M (free; aliased as ctx)
    short* vtw  = vw + NTOK;             // 4M (V written transposed by gemm_qkv)
    short* ctxw = vw;
    float* maddg = (float*)(vtw + NTOK); // 4096 floats

    dim3 blk(256);
    cvt_all<<<dim3(8194), blk, 0, stream>>>(x, Wq, Wk, Wv, Wo, mask, xb, wqkv, wob, maddg);
    gemm_qkv<<<dim3(32, 24), blk, 0, stream>>>(xb, wqkv, bq, bk, bv, qw, kw, vtw);
    attn_kernel<<<dim3(32 * 32), blk, 0, stream>>>(qw, kw, vtw, maddg, ctxw);
    gemm_o<<<dim3(32, 16), blk, 0, stream>>>(ctxw, wob, bo, x, out);
    ln_kernel<<<BATCH * SEQ, blk, 0, stream>>>(out, gamma, beta);
}

// Round 9
// 227.041 us; speedup vs baseline: 1.0480x; 1.0118x over previous
//
#include <hip/hip_runtime.h>
#include <hip/hip_bf16.h>

#define DM   1024
#define HEADS 16
#define DH    64
#define SEQ  2048
#define BATCH   2
#define LOG2E 1.44269504088896f

typedef __attribute__((ext_vector_type(8))) short short8;
typedef __attribute__((ext_vector_type(4))) short bf16x4;
typedef __attribute__((ext_vector_type(4))) float floatx4;
typedef __attribute__((ext_vector_type(16))) float floatx16;

__device__ __forceinline__ short f2b(float f) {
    union { float f; unsigned u; } v; v.f = f;
    unsigned r = v.u + 0x7FFFu + ((v.u >> 16) & 1u);
    return (short)(r >> 16);
}

#if __has_builtin(__builtin_amdgcn_exp2f)
__device__ __forceinline__ float fexp2(float x) { return __builtin_amdgcn_exp2f(x); }
#else
__device__ __forceinline__ float fexp2(float x) { return exp2f(x); }
#endif

__device__ __forceinline__ void async_copy16(const short* gsrc, short* ldst) {
    __builtin_amdgcn_global_load_lds(
        (const __attribute__((address_space(1))) void*)gsrc,
        (__attribute__((address_space(3))) void*)ldst,
        16, 0, 0);
}

// Fused fp32->bf16 conversion of x, Wq, Wk, Wv, Wo + mask-add table (log2 domain).
__global__ __launch_bounds__(256) void cvt_all(const float* __restrict__ x,
        const float* __restrict__ wq, const float* __restrict__ wk,
        const float* __restrict__ wv, const float* __restrict__ wo,
        const float* __restrict__ mask,
        short* __restrict__ xb, short* __restrict__ wqkv, short* __restrict__ wob,
        float* __restrict__ maddg)
{
    const int b = blockIdx.x;
    if (b >= 8192) {            // mask prep: maddg = (1-mask) * (-1e5 * log2e)
        const int bb = b - 8192;
        const float* mrow = mask + (size_t)bb * SEQ;
        float* mg = maddg + (size_t)bb * SEQ;
#pragma unroll
        for (int i = 0; i < 8; ++i) {
            const int idx = threadIdx.x * 8 + i;
            mg[idx] = (1.f - mrow[idx]) * (-100000.f * LOG2E);
        }
        return;
    }
    const float* src; short* dst; int idx;
    if (b < 4096)      { src = x;  dst = xb;                idx = b; }
    else if (b < 5120) { src = wq; dst = wqkv;              idx = b - 4096; }
    else if (b < 6144) { src = wk; dst = wqkv + (1 << 20);  idx = b - 5120; }
    else if (b < 7168) { src = wv; dst = wqkv + (2 << 20);  idx = b - 6144; }
    else               { src = wo; dst = wob;               idx = b - 7168; }
    const int i = idx * 256 + threadIdx.x;
    floatx4 v = ((const floatx4*)src)[i];
    bf16x4 o;
    o.x = f2b(v.x); o.y = f2b(v.y); o.z = f2b(v.z); o.w = f2b(v.w);
    ((bf16x4*)dst)[i] = o;
}

// Fused QKV GEMM (m97 structure, 128x128 tile, BK=32). B rows: Wq|Wk|Wv.
// Q pre-scaled by 0.125*log2e (exp2-domain softmax). Q/K in [b,h,s,dh].
// V written DIRECTLY transposed to vt [b,h,dh,s] (4 consecutive-r acc values
// are contiguous there -> one bf16x4 store). transpose_v kernel deleted.
__global__ __launch_bounds__(256) void gemm_qkv(const short* __restrict__ A,
        const short* __restrict__ B,
        const float* __restrict__ bq, const float* __restrict__ bk,
        const float* __restrict__ bv,
        short* __restrict__ qw, short* __restrict__ kw, short* __restrict__ vt)
{
    __shared__ short As[128 * 32];
    __shared__ short Bs[128 * 32];
    const int m0 = blockIdx.x * 128, n0 = blockIdx.y * 128;
    const int w = threadIdx.x >> 6, lane = threadIdx.x & 63;
    const int l16 = lane & 15, quad = lane >> 4;
    const int wm = w >> 1, wn = w & 1;
    const int lr = lane >> 2, lc = (lane & 3) * 8;

    floatx4 acc[4][4];
#pragma unroll
    for (int i = 0; i < 4; ++i)
#pragma unroll
        for (int j = 0; j < 4; ++j) acc[i][j] = (floatx4){0.f, 0.f, 0.f, 0.f};

    for (int kt = 0; kt < DM / 32; ++kt) {
        const int k0 = kt * 32;
        __syncthreads();
        async_copy16(A + (size_t)(m0 + w * 32 + lr) * DM + k0 + lc,      &As[w * 1024]);
        async_copy16(A + (size_t)(m0 + w * 32 + 16 + lr) * DM + k0 + lc, &As[w * 1024 + 512]);
        async_copy16(B + (size_t)(n0 + w * 32 + lr) * DM + k0 + lc,      &Bs[w * 1024]);
        async_copy16(B + (size_t)(n0 + w * 32 + 16 + lr) * DM + k0 + lc, &Bs[w * 1024 + 512]);
        __syncthreads();

        short8 af[4], bf[4];
#pragma unroll
        for (int i = 0; i < 4; ++i)
            af[i] = *(const short8*)&As[(wm * 64 + i * 16 + l16) * 32 + quad * 8];
#pragma unroll
        for (int j = 0; j < 4; ++j)
            bf[j] = *(const short8*)&Bs[(wn * 64 + j * 16 + l16) * 32 + quad * 8];
#pragma unroll
        for (int i = 0; i < 4; ++i)
#pragma unroll
            for (int j = 0; j < 4; ++j)
                acc[i][j] = __builtin_amdgcn_mfma_f32_16x16x32_bf16(af[i], bf[j], acc[i][j], 0, 0, 0);
    }

    const int m_base = m0 + wm * 64 + quad * 4;
    const int t = n0 >> 10;                  // block-uniform: q/k/v select
#pragma unroll
    for (int j = 0; j < 4; ++j) {
        const int nb = n0 + wn * 64 + j * 16;
        const int nn = (nb & 1023) + l16;
        const int h = nn >> 6, dh = nn & 63;
        if (t == 2) {                        // V -> vt [b,h,dh,s], vectorized
            const float bvv = bv[nn];
#pragma unroll
            for (int i = 0; i < 4; ++i) {
                const int m = m_base + i * 16;
                const int b = m >> 11, s = m & (SEQ - 1);
                bf16x4 o;
                o.x = f2b(acc[i][j][0] + bvv);
                o.y = f2b(acc[i][j][1] + bvv);
                o.z = f2b(acc[i][j][2] + bvv);
                o.w = f2b(acc[i][j][3] + bvv);
                *(bf16x4*)&vt[(((size_t)(b * HEADS + h)) * DH + dh) * SEQ + s] = o;
            }
        } else {                             // Q/K -> [b,h,s,dh] scatter
            const float* bias = (t == 0) ? bq : bk;
            short* dst = (t == 0) ? qw : kw;
            const float mulf = (t == 0) ? (0.125f * LOG2E) : 1.0f;
            const float bvv = bias[nn];
#pragma unroll
            for (int i = 0; i < 4; ++i)
#pragma unroll
                for (int r = 0; r < 4; ++r) {
                    const int m = m_base + i * 16 + r;
                    const int b = m >> 11, s = m & (SEQ - 1);
                    dst[(((size_t)(b * HEADS + h)) * SEQ + s) * DH + dh] =
                        f2b((acc[i][j][r] + bvv) * mulf);
                }
        }
    }
}

// Flash attention, 32x32x16 MFMA formulation.
// ROUND-8 CHANGE: mask row staged ONCE into LDS in the prologue; md reads
// become broadcast ds_read_b128 (was: 4 GLOBAL loads per thread per iter,
// issued ~50cy before their vmcnt drain -> ~200-900cy L2 latency exposed
// EVERY iteration — the dominant per-iter stall per the R8 cycle audit).
// Arena back to 40960B (R6/R8 proved 32768 vs 40960 doesn't change occupancy,
// so the 8KB is free). vmcnt FIFO unchanged: prologue mask(2)+K0(2) drain
// under iter-0's vmcnt(4); steady-state 4/2; last iter 2/0. V-before-K
// sched_barrier pin kept (vmcnt(2) window depends on issue order).
// Arena: K2(16K) + V(8K) + P(8K) + mask(8K) = 40960B. Ct+l_fin alias K bufs.
// Layouts: A/B 32x32x16: m(n)=lane&31, k=8*(lane>>5)+j. C/D: col=lane&31,
// row=(reg&3)+8*(reg>>2)+4*(lane>>5)  [m74/m101-verified].
__global__ __launch_bounds__(256) void attn_kernel(const short* __restrict__ q,
        const short* __restrict__ k, const short* __restrict__ vt,
        const float* __restrict__ maddg, short* __restrict__ ctx)
{
    const int id    = blockIdx.x;
    const int qtile = id >> 5;             // id = qtile*32 + bh
    const int bh    = id & 31;
    const int bidx  = bh >> 4;
    const int wave = threadIdx.x >> 6, lane = threadIdx.x & 63;
    const int l32 = lane & 31, half = lane >> 5;
    const int kw = wave & 1, qw = wave >> 1;   // S^T: keys kw*32.., qrows qw*32..
                                               // PV: dh kw*32.., qrows qw*32..

    // LDS arena (shorts), 20480 shorts = 40960 B:
    //  [    0.. 4096) k buf0   [ 4096.. 8192) k buf1
    //  [ 8192..12288) v buf (single)
    //  [12288..16384) p_lds
    //  [16384..20480) mask row (2048 floats)
    //  epilogue (K bufs retired): Ct = shorts [0..4608),
    //                             l_fin = floats at short-offset 4608
    __shared__ __align__(16) short smem[20480];
    short* p_lds    = smem + 12288;
    float* mask_lds = (float*)(smem + 16384);
    short* Ct       = smem;
    float* l_fin    = (float*)(smem + 4608);

    const short* kbase0 = k  + (size_t)bh * SEQ * DH;
    const short* vbase0 = vt + (size_t)bh * DH * SEQ;
    const float* mrow   = maddg + (size_t)bidx * SEQ;

    // Q B-frags: B[n=qrow=l32][k=dh = kk*16 + half*8 + j]
    const int qrow = qtile * 64 + qw * 32 + l32;
    const short* qbase = q + ((size_t)bh * SEQ + qrow) * DH;
    short8 b_q[4];
#pragma unroll
    for (int kk = 0; kk < 4; ++kk)
        b_q[kk] = *(const short8*)(qbase + kk * 16 + half * 8);

    floatx16 oacc;
#pragma unroll
    for (int r = 0; r < 16; ++r) oacc[r] = 0.f;
    float l_run = 0.f;

    // staging geometry: 512 chunks/tile, 256 threads -> 2 chunks/thread/array
    int srw[2], gg[2];
#pragma unroll
    for (int i = 0; i < 2; ++i) {
        const int slot = i * 256 + wave * 64 + lane;
        srw[i] = slot >> 3;
        gg[i]  = (slot & 7) ^ (srw[i] & 7);
    }

    const int prow = qw * 32 + l32;        // this lane's qrow (local 0..63)

    auto stage_k = [&](int buf, int kt) {
        const short* kbase = kbase0 + (size_t)(kt * 64) * DH;
        const int ko = buf << 12;
#pragma unroll
        for (int i = 0; i < 2; ++i)
            async_copy16(kbase + srw[i] * DH + gg[i] * 8,
                         &smem[ko + (i * 256 + wave * 64) * 8]);
    };
    auto stage_v = [&](int kt) {
        const short* vbase = vbase0 + kt * 64;
#pragma unroll
        for (int i = 0; i < 2; ++i)
            async_copy16(vbase + (size_t)srw[i] * SEQ + gg[i] * 8,
                         &smem[8192 + (i * 256 + wave * 64) * 8]);
    };

    // prologue: mask row (2 copies/thread) + K tile 0 (2 copies/thread).
    // Both drained by iter-0's vmcnt(4) — no order pin needed between them.
#pragma unroll
    for (int i = 0; i < 2; ++i)
        async_copy16((const short*)mrow + (i * 256 + threadIdx.x) * 8,
                     &smem[16384 + (i * 256 + wave * 64) * 8]);
    stage_k(0, 0);

    int cur = 0;
    for (int kt = 0; kt < SEQ / 64; ++kt) {
        // B1: prev-iter reads of vbuf / p_lds complete; kbuf[cur^1] retired
        asm volatile("" ::: "memory");
        __builtin_amdgcn_s_barrier();

        // mask C-init from LDS (broadcast ds_read_b128 — not in vmcnt FIFO)
        floatx4 md[4];
#pragma unroll
        for (int g = 0; g < 4; ++g)
            md[g] = *(const floatx4*)&mask_lds[kt * 64 + kw * 32 + 8 * g + 4 * half];

        // staging FIFO: V(kt)(2) -> K(kt+1)(2); invariant: K(kt)x2 outstanding
        stage_v(kt);
        __builtin_amdgcn_sched_barrier(0);   // pin: V issues before K issues
        const bool has_next = (kt + 1 < SEQ / 64);
        if (has_next) {
            stage_k(cur ^ 1, kt + 1);
            // drain K(kt) (+ prologue mask at kt=0); keep V(kt)x2 + K(kt+1)x2
            asm volatile("s_waitcnt vmcnt(4)" ::: "memory");
        } else {
            // drain K(kt); keep V(kt)x2
            asm volatile("s_waitcnt vmcnt(2)" ::: "memory");
        }
        __builtin_amdgcn_s_barrier();      // B2: kbuf[cur] (+mask) landed

        // S^T = K Q^T (log2 domain), 4 MFMA 32x32x16, C init = mask
        floatx16 s;
#pragma unroll
        for (int g = 0; g < 4; ++g)
#pragma unroll
            for (int r = 0; r < 4; ++r) s[g * 4 + r] = md[g][r];
        {
            const int ko = cur << 12;
            const int krow = kw * 32 + l32;
            const int ksw = krow & 7;
#pragma unroll
            for (int kk = 0; kk < 4; ++kk) {
                const int c = kk * 2 + half;
                short8 a = *(const short8*)&smem[ko + krow * 64 + ((c ^ ksw) * 8)];
                s = __builtin_amdgcn_mfma_f32_32x32x16_bf16(a, b_q[kk], s, 0, 0, 0);
            }
        }

        // p = exp2(min(s,40)); private row-sum; packed stores to p_lds [qrow][key]
        float lsum = 0.f;
        const int psw = prow & 7;
#pragma unroll
        for (int g = 0; g < 4; ++g) {
            const float p0 = fexp2(fminf(s[g * 4 + 0], 40.f));
            const float p1 = fexp2(fminf(s[g * 4 + 1], 40.f));
            const float p2 = fexp2(fminf(s[g * 4 + 2], 40.f));
            const float p3 = fexp2(fminf(s[g * 4 + 3], 40.f));
            lsum += (p0 + p1) + (p2 + p3);
            union { __hip_bfloat162 h[2]; bf16x4 v; } u;
            u.h[0] = __float22bfloat162_rn(make_float2(p0, p1));
            u.h[1] = __float22bfloat162_rn(make_float2(p2, p3));
            const int c = kw * 4 + g;      // chunk of key offset kw*32+8g
            *(bf16x4*)&p_lds[prow * 64 + ((c ^ psw) * 8) + 4 * half] = u.v;
        }
        l_run += lsum;                     // deferred cross-wave combine

        // B3: P visible + V(kt) landed (keep K(kt+1) prefetch in flight)
        asm volatile("s_waitcnt lgkmcnt(0)" ::: "memory");
        if (has_next) {
            asm volatile("s_waitcnt vmcnt(2)" ::: "memory");
        } else {
            asm volatile("s_waitcnt vmcnt(0)" ::: "memory");
        }
        __builtin_amdgcn_s_barrier();

        // O^T += V^T P^T : A=V^T[dh][key], B=P[qrow][key], 4 MFMA 32x32x16
        {
            const int vrow = kw * 32 + l32;    // dh row
            const int vsw = vrow & 7;
#pragma unroll
            for (int kk = 0; kk < 4; ++kk) {
                const int c = kk * 2 + half;
                short8 av = *(const short8*)&smem[8192 + vrow * 64 + ((c ^ vsw) * 8)];
                short8 bp = *(const short8*)&p_lds[prow * 64 + ((c ^ psw) * 8)];
                oacc = __builtin_amdgcn_mfma_f32_32x32x16_bf16(av, bp, oacc, 0, 0, 0);
            }
        }
        cur ^= 1;
    }

    // E1: loop fully done; K-buffer region retires for Ct/l_fin reuse
    asm volatile("" ::: "memory");
    __builtin_amdgcn_s_barrier();

    // cross-half + cross-wave l combine (once): halves share qrow via shfl,
    // kw-pair shares via LDS.
    const float l_mine = l_run + __shfl_xor(l_run, 32);
    l_fin[kw * 64 + prow] = l_mine;        // dup write from both halves, same value
    asm volatile("s_waitcnt lgkmcnt(0)" ::: "memory");
    __builtin_amdgcn_s_barrier();          // E2: l_fin visible

    // epilogue: O^T[dh][qrow] / l -> Ct[qrow][dh] -> coalesced global stores
    const int h = bh & 15, bb = bh >> 4;
    const float rl = 1.f / (l_fin[prow] + l_fin[64 + prow]);
#pragma unroll
    for (int g = 0; g < 4; ++g) {
        bf16x4 p;
        p.x = f2b(oacc[g * 4 + 0] * rl);
        p.y = f2b(oacc[g * 4 + 1] * rl);
        p.z = f2b(oacc[g * 4 + 2] * rl);
        p.w = f2b(oacc[g * 4 + 3] * rl);
        const int dh = kw * 32 + 8 * g + 4 * half;   // row=(reg&3)+8g+4*half
        *(bf16x4*)&Ct[prow * 72 + dh] = p;
    }
    __syncthreads();                       // E3
    {
        const int row = threadIdx.x >> 2, ch = threadIdx.x & 3;
        short8 v0 = *(const short8*)&Ct[row * 72 + ch * 16];
        short8 v1 = *(const short8*)&Ct[row * 72 + ch * 16 + 8];
        short* gp = ctx + ((size_t)(bb * SEQ + qtile * 64 + row)) * DM + h * 64 + ch * 16;
        *(short8*)gp = v0;
        *(short8*)(gp + 8) = v1;
    }
}

// Output GEMM + bias + residual (fp32 out into d_out). 128x64 tile, 2 blocks/CU.
__global__ __launch_bounds__(256) void gemm_o(const short* __restrict__ A,
        const short* __restrict__ B, const float* __restrict__ bo,
        const float* __restrict__ xin, float* __restrict__ out)
{
    __shared__ short As[128 * 32];
    __shared__ short Bs[64 * 32];
    const int m0 = blockIdx.x * 128, n0 = blockIdx.y * 64;
    const int w = threadIdx.x >> 6, lane = threadIdx.x & 63;
    const int l16 = lane & 15, quad = lane >> 4;
    const int wm = w >> 1, wn = w & 1;     // wave: 64 rows x 32 cols

    floatx4 acc[4][2];
#pragma unroll
    for (int i = 0; i < 4; ++i)
#pragma unroll
        for (int j = 0; j < 2; ++j) acc[i][j] = (floatx4){0.f, 0.f, 0.f, 0.f};

    const int c0 = w * 64 + lane;

    for (int kt = 0; kt < DM / 32; ++kt) {
        const int k0 = kt * 32;
        __syncthreads();
        {
            const int ra0 = c0 >> 2,          ca0 = (c0 & 3) * 8;
            const int ra1 = (256 + c0) >> 2,  ca1 = (c0 & 3) * 8;
            async_copy16(A + (size_t)(m0 + ra0) * DM + k0 + ca0, &As[(w * 64) * 8]);
            async_copy16(A + (size_t)(m0 + ra1) * DM + k0 + ca1, &As[(256 + w * 64) * 8]);
            const int rb = c0 >> 2, cb = (c0 & 3) * 8;
            async_copy16(B + (size_t)(n0 + rb) * DM + k0 + cb,   &Bs[(w * 64) * 8]);
        }
        __syncthreads();

        short8 af[4], bf[2];
#pragma unroll
        for (int i = 0; i < 4; ++i)
            af[i] = *(const short8*)&As[(wm * 64 + i * 16 + l16) * 32 + quad * 8];
#pragma unroll
        for (int j = 0; j < 2; ++j)
            bf[j] = *(const short8*)&Bs[(wn * 32 + j * 16 + l16) * 32 + quad * 8];
#pragma unroll
        for (int i = 0; i < 4; ++i)
#pragma unroll
            for (int j = 0; j < 2; ++j)
                acc[i][j] = __builtin_amdgcn_mfma_f32_16x16x32_bf16(af[i], bf[j], acc[i][j], 0, 0, 0);
    }

    const int m_base = m0 + wm * 64 + quad * 4;
#pragma unroll
    for (int j = 0; j < 2; ++j) {
        const int n = n0 + wn * 32 + j * 16 + l16;
        const float bvv = bo[n];
#pragma unroll
        for (int i = 0; i < 4; ++i)
#pragma unroll
            for (int r = 0; r < 4; ++r) {
                const int m = m_base + i * 16 + r;
                const size_t idx = (size_t)m * DM + n;
                out[idx] = acc[i][j][r] + bvv + xin[idx];
            }
    }
}

__global__ __launch_bounds__(256) void ln_kernel(float* __restrict__ y,
        const float* __restrict__ gamma, const float* __restrict__ beta)
{
    const int row = blockIdx.x;
    const int t = threadIdx.x;
    const int wave = t >> 6, lane = t & 63;
    const floatx4 v = ((const floatx4*)(y + (size_t)row * DM))[t];
    float s  = v.x + v.y + v.z + v.w;
    float q2 = v.x * v.x + v.y * v.y + v.z * v.z + v.w * v.w;
#pragma unroll
    for (int off = 1; off < 64; off <<= 1) {
        s  += __shfl_xor(s, off);
        q2 += __shfl_xor(q2, off);
    }
    __shared__ float rs[4], rq[4];
    if (lane == 0) { rs[wave] = s; rq[wave] = q2; }
    __syncthreads();
    const float S  = rs[0] + rs[1] + rs[2] + rs[3];
    const float Q2 = rq[0] + rq[1] + rq[2] + rq[3];
    const float mu = S * (1.f / DM);
    float var = Q2 * (1.f / DM) - mu * mu;
    var = fmaxf(var, 0.f);
    const float rstd = rsqrtf(var + 1e-12f);
    const floatx4 g = ((const floatx4*)gamma)[t];
    const floatx4 bt = ((const floatx4*)beta)[t];
    floatx4 o;
    o.x = (v.x - mu) * rstd * g.x + bt.x;
    o.y = (v.y - mu) * rstd * g.y + bt.y;
    o.z = (v.z - mu) * rstd * g.z + bt.z;
    o.w = (v.w - mu) * rstd * g.w + bt.w;
    ((floatx4*)(y + (size_t)row * DM))[t] = o;
}

extern "C" void kernel_launch(void* const* d_in, const int* in_sizes, int n_in,
                              void* d_out, int out_size, void* d_ws, size_t ws_size,
                              hipStream_t stream) {
    const float* x     = (const float*)d_in[0];
    const float* mask  = (const float*)d_in[1];
    const float* Wq    = (const float*)d_in[2];
    const float* bq    = (const float*)d_in[3];
    const float* Wk    = (const float*)d_in[4];
    const float* bk    = (const float*)d_in[5];
    const float* Wv    = (const float*)d_in[6];
    const float* bv    = (const float*)d_in[7];
    const float* Wo    = (const float*)d_in[8];
    const float* bo    = (const float*)d_in[9];
    const float* gamma = (const float*)d_in[10];
    const float* beta  = (const float*)d_in[11];
    float* out = (float*)d_out;

    const size_t NTOK = (size_t)BATCH * SEQ * DM;       // 4M
    const size_t WSZ  = (size_t)DM * DM;                // 1M
    short* xb   = (short*)d_ws;          // 4M shorts
    short* wqkv = xb + NTOK;             // 3M
    short* wob  = wqkv + 3 * WSZ;        // 1M
    short* qw   = wob + WSZ;             // 4M
    short* kw   = qw + NTOK;             // 4M
    short* vw   = kw + NTOK;             // 4M (free; aliased as ctx)
    short* vtw  = vw + NTOK;             // 4M (V written transposed by gemm_qkv)
    short* ctxw = vw;
    float* maddg = (float*)(vtw + NTOK); // 4096 floats

    dim3 blk(256);
    cvt_all<<<dim3(8194), blk, 0, stream>>>(x, Wq, Wk, Wv, Wo, mask, xb, wqkv, wob, maddg);
    gemm_qkv<<<dim3(32, 24), blk, 0, stream>>>(xb, wqkv, bq, bk, bv, qw, kw, vtw);
    attn_kernel<<<dim3(32 * 32), blk, 0, stream>>>(qw, kw, vtw, maddg, ctxw);
    gemm_o<<<dim3(32, 16), blk, 0, stream>>>(ctxw, wob, bo, x, out);
    ln_kernel<<<BATCH * SEQ, blk, 0, stream>>>(out, gamma, beta);
}

// Round 10
// 225.919 us; speedup vs baseline: 1.0532x; 1.0050x over previous
//
#include <hip/hip_runtime.h>
#include <hip/hip_bf16.h>

#define DM   1024
#define HEADS 16
#define DH    64
#define SEQ  2048
#define BATCH   2
#define LOG2E 1.44269504088896f

typedef __attribute__((ext_vector_type(8))) short short8;
typedef __attribute__((ext_vector_type(4))) short bf16x4;
typedef __attribute__((ext_vector_type(4))) float floatx4;
typedef __attribute__((ext_vector_type(16))) float floatx16;

__device__ __forceinline__ short f2b(float f) {
    union { float f; unsigned u; } v; v.f = f;
    unsigned r = v.u + 0x7FFFu + ((v.u >> 16) & 1u);
    return (short)(r >> 16);
}

#if __has_builtin(__builtin_amdgcn_exp2f)
__device__ __forceinline__ float fexp2(float x) { return __builtin_amdgcn_exp2f(x); }
#else
__device__ __forceinline__ float fexp2(float x) { return exp2f(x); }
#endif

__device__ __forceinline__ void async_copy16(const short* gsrc, short* ldst) {
    __builtin_amdgcn_global_load_lds(
        (const __attribute__((address_space(1))) void*)gsrc,
        (__attribute__((address_space(3))) void*)ldst,
        16, 0, 0);
}

// Fused fp32->bf16 conversion of x, Wq, Wk, Wv, Wo + mask-add table (log2 domain).
__global__ __launch_bounds__(256) void cvt_all(const float* __restrict__ x,
        const float* __restrict__ wq, const float* __restrict__ wk,
        const float* __restrict__ wv, const float* __restrict__ wo,
        const float* __restrict__ mask,
        short* __restrict__ xb, short* __restrict__ wqkv, short* __restrict__ wob,
        float* __restrict__ maddg)
{
    const int b = blockIdx.x;
    if (b >= 8192) {            // mask prep: maddg = (1-mask) * (-1e5 * log2e)
        const int bb = b - 8192;
        const float* mrow = mask + (size_t)bb * SEQ;
        float* mg = maddg + (size_t)bb * SEQ;
#pragma unroll
        for (int i = 0; i < 8; ++i) {
            const int idx = threadIdx.x * 8 + i;
            mg[idx] = (1.f - mrow[idx]) * (-100000.f * LOG2E);
        }
        return;
    }
    const float* src; short* dst; int idx;
    if (b < 4096)      { src = x;  dst = xb;                idx = b; }
    else if (b < 5120) { src = wq; dst = wqkv;              idx = b - 4096; }
    else if (b < 6144) { src = wk; dst = wqkv + (1 << 20);  idx = b - 5120; }
    else if (b < 7168) { src = wv; dst = wqkv + (2 << 20);  idx = b - 6144; }
    else               { src = wo; dst = wob;               idx = b - 7168; }
    const int i = idx * 256 + threadIdx.x;
    floatx4 v = ((const floatx4*)src)[i];
    bf16x4 o;
    o.x = f2b(v.x); o.y = f2b(v.y); o.z = f2b(v.z); o.w = f2b(v.w);
    ((bf16x4*)dst)[i] = o;
}

// Fused QKV GEMM (m97 structure, 128x128 tile, BK=32). B rows: Wq|Wk|Wv.
// Q pre-scaled by 0.125*log2e (exp2-domain softmax). Q/K in [b,h,s,dh].
// ROUND-9 CHANGE: V epilogue via LDS-staged transpose. The R5 direct vt
// stores were 8B bf16x4 at 4KB stride (16 cachelines per quarter-wave) —
// ledger shows they cost gemm_qkv ~8µs (R4->R6: transpose_v deleted −4µs
// but total +4.4). Now: stage C-tile [n][m] in LDS (pad +4 shorts: writes
// hit banks 2*l16 — distinct; reads row-contiguous), then store vt rows as
// quarter-wave-contiguous 256B runs (16 lanes x 16B along s).
// LDS 33KB (union over As/Bs, barrier-guarded); grid 3 blocks/CU unaffected.
// Q/K scatter epilogue unchanged (prior session: measured best of 3).
__global__ __launch_bounds__(256) void gemm_qkv(const short* __restrict__ A,
        const short* __restrict__ B,
        const float* __restrict__ bq, const float* __restrict__ bk,
        const float* __restrict__ bv,
        short* __restrict__ qw, short* __restrict__ kw, short* __restrict__ vt)
{
    // union arena: As = [0..4096), Bs = [4096..8192) shorts during main loop;
    // Cv = [0..16896) shorts (128 rows x 132) in the V epilogue (after barrier).
    __shared__ __align__(16) short gsm[16896];
    short* As = gsm;
    short* Bs = gsm + 4096;
    const int m0 = blockIdx.x * 128, n0 = blockIdx.y * 128;
    const int w = threadIdx.x >> 6, lane = threadIdx.x & 63;
    const int l16 = lane & 15, quad = lane >> 4;
    const int wm = w >> 1, wn = w & 1;
    const int lr = lane >> 2, lc = (lane & 3) * 8;

    floatx4 acc[4][4];
#pragma unroll
    for (int i = 0; i < 4; ++i)
#pragma unroll
        for (int j = 0; j < 4; ++j) acc[i][j] = (floatx4){0.f, 0.f, 0.f, 0.f};

    for (int kt = 0; kt < DM / 32; ++kt) {
        const int k0 = kt * 32;
        __syncthreads();
        async_copy16(A + (size_t)(m0 + w * 32 + lr) * DM + k0 + lc,      &As[w * 1024]);
        async_copy16(A + (size_t)(m0 + w * 32 + 16 + lr) * DM + k0 + lc, &As[w * 1024 + 512]);
        async_copy16(B + (size_t)(n0 + w * 32 + lr) * DM + k0 + lc,      &Bs[w * 1024]);
        async_copy16(B + (size_t)(n0 + w * 32 + 16 + lr) * DM + k0 + lc, &Bs[w * 1024 + 512]);
        __syncthreads();

        short8 af[4], bf[4];
#pragma unroll
        for (int i = 0; i < 4; ++i)
            af[i] = *(const short8*)&As[(wm * 64 + i * 16 + l16) * 32 + quad * 8];
#pragma unroll
        for (int j = 0; j < 4; ++j)
            bf[j] = *(const short8*)&Bs[(wn * 64 + j * 16 + l16) * 32 + quad * 8];
#pragma unroll
        for (int i = 0; i < 4; ++i)
#pragma unroll
            for (int j = 0; j < 4; ++j)
                acc[i][j] = __builtin_amdgcn_mfma_f32_16x16x32_bf16(af[i], bf[j], acc[i][j], 0, 0, 0);
    }

    const int m_base = m0 + wm * 64 + quad * 4;
    const int t = n0 >> 10;                  // block-uniform: q/k/v select

    if (t == 2) {
        // ---- V epilogue: LDS-staged transpose -> coalesced vt stores ----
        __syncthreads();                     // retire As/Bs before Cv overwrite
#pragma unroll
        for (int j = 0; j < 4; ++j) {
            const int nl = wn * 64 + j * 16 + l16;            // local n (row)
            const float bvv = bv[((n0 + wn * 64 + j * 16) & 1023) + l16];
#pragma unroll
            for (int i = 0; i < 4; ++i) {
                bf16x4 o;
                o.x = f2b(acc[i][j][0] + bvv);
                o.y = f2b(acc[i][j][1] + bvv);
                o.z = f2b(acc[i][j][2] + bvv);
                o.w = f2b(acc[i][j][3] + bvv);
                *(bf16x4*)&gsm[nl * 132 + wm * 64 + quad * 4 + i * 16] = o;
            }
        }
        __syncthreads();
        const int b = m0 >> 11;
        const int s0 = m0 & (SEQ - 1);
        const int hbase = (n0 & 1023) >> 6;
        const int ch = threadIdx.x & 15;
        const int rbase = threadIdx.x >> 4;  // 0..15
#pragma unroll
        for (int p = 0; p < 8; ++p) {
            const int row = p * 16 + rbase;                   // local n 0..127
            const int h = hbase + (row >> 6), dh = row & 63;
            short8 vv = *(const short8*)&gsm[row * 132 + ch * 8];
            *(short8*)&vt[(((size_t)(b * HEADS + h)) * DH + dh) * SEQ + s0 + ch * 8] = vv;
        }
        return;
    }

    // ---- Q/K epilogue: scatter (measured best of 3 variants) ----
#pragma unroll
    for (int j = 0; j < 4; ++j) {
        const int nb = n0 + wn * 64 + j * 16;
        const int nn = (nb & 1023) + l16;
        const int h = nn >> 6, dh = nn & 63;
        const float* bias = (t == 0) ? bq : bk;
        short* dst = (t == 0) ? qw : kw;
        const float mulf = (t == 0) ? (0.125f * LOG2E) : 1.0f;
        const float bvv = bias[nn];
#pragma unroll
        for (int i = 0; i < 4; ++i)
#pragma unroll
            for (int r = 0; r < 4; ++r) {
                const int m = m_base + i * 16 + r;
                const int b = m >> 11, s = m & (SEQ - 1);
                dst[(((size_t)(b * HEADS + h)) * SEQ + s) * DH + dh] =
                    f2b((acc[i][j][r] + bvv) * mulf);
            }
    }
}

// Flash attention, 32x32x16 MFMA formulation.
// (R9-verified: 66.2 µs. Mask row staged once into LDS; single-buffered V;
// double-buffered K with counted vmcnt FIFO; occ ~31%.)
// Arena: K2(16K) + V(8K) + P(8K) + mask(8K) = 40960B. Ct+l_fin alias K bufs.
// Layouts: A/B 32x32x16: m(n)=lane&31, k=8*(lane>>5)+j. C/D: col=lane&31,
// row=(reg&3)+8*(reg>>2)+4*(lane>>5)  [m74/m101-verified].
__global__ __launch_bounds__(256) void attn_kernel(const short* __restrict__ q,
        const short* __restrict__ k, const short* __restrict__ vt,
        const float* __restrict__ maddg, short* __restrict__ ctx)
{
    const int id    = blockIdx.x;
    const int qtile = id >> 5;             // id = qtile*32 + bh
    const int bh    = id & 31;
    const int bidx  = bh >> 4;
    const int wave = threadIdx.x >> 6, lane = threadIdx.x & 63;
    const int l32 = lane & 31, half = lane >> 5;
    const int kw = wave & 1, qw = wave >> 1;   // S^T: keys kw*32.., qrows qw*32..
                                               // PV: dh kw*32.., qrows qw*32..

    __shared__ __align__(16) short smem[20480];
    short* p_lds    = smem + 12288;
    float* mask_lds = (float*)(smem + 16384);
    short* Ct       = smem;
    float* l_fin    = (float*)(smem + 4608);

    const short* kbase0 = k  + (size_t)bh * SEQ * DH;
    const short* vbase0 = vt + (size_t)bh * DH * SEQ;
    const float* mrow   = maddg + (size_t)bidx * SEQ;

    // Q B-frags: B[n=qrow=l32][k=dh = kk*16 + half*8 + j]
    const int qrow = qtile * 64 + qw * 32 + l32;
    const short* qbase = q + ((size_t)bh * SEQ + qrow) * DH;
    short8 b_q[4];
#pragma unroll
    for (int kk = 0; kk < 4; ++kk)
        b_q[kk] = *(const short8*)(qbase + kk * 16 + half * 8);

    floatx16 oacc;
#pragma unroll
    for (int r = 0; r < 16; ++r) oacc[r] = 0.f;
    float l_run = 0.f;

    // staging geometry: 512 chunks/tile, 256 threads -> 2 chunks/thread/array
    int srw[2], gg[2];
#pragma unroll
    for (int i = 0; i < 2; ++i) {
        const int slot = i * 256 + wave * 64 + lane;
        srw[i] = slot >> 3;
        gg[i]  = (slot & 7) ^ (srw[i] & 7);
    }

    const int prow = qw * 32 + l32;        // this lane's qrow (local 0..63)

    auto stage_k = [&](int buf, int kt) {
        const short* kbase = kbase0 + (size_t)(kt * 64) * DH;
        const int ko = buf << 12;
#pragma unroll
        for (int i = 0; i < 2; ++i)
            async_copy16(kbase + srw[i] * DH + gg[i] * 8,
                         &smem[ko + (i * 256 + wave * 64) * 8]);
    };
    auto stage_v = [&](int kt) {
        const short* vbase = vbase0 + kt * 64;
#pragma unroll
        for (int i = 0; i < 2; ++i)
            async_copy16(vbase + (size_t)srw[i] * SEQ + gg[i] * 8,
                         &smem[8192 + (i * 256 + wave * 64) * 8]);
    };

    // prologue: mask row (2 copies/thread) + K tile 0 (2 copies/thread).
#pragma unroll
    for (int i = 0; i < 2; ++i)
        async_copy16((const short*)mrow + (i * 256 + threadIdx.x) * 8,
                     &smem[16384 + (i * 256 + wave * 64) * 8]);
    stage_k(0, 0);

    int cur = 0;
    for (int kt = 0; kt < SEQ / 64; ++kt) {
        // B1: prev-iter reads of vbuf / p_lds complete; kbuf[cur^1] retired
        asm volatile("" ::: "memory");
        __builtin_amdgcn_s_barrier();

        // mask C-init from LDS (broadcast ds_read_b128 — not in vmcnt FIFO)
        floatx4 md[4];
#pragma unroll
        for (int g = 0; g < 4; ++g)
            md[g] = *(const floatx4*)&mask_lds[kt * 64 + kw * 32 + 8 * g + 4 * half];

        // staging FIFO: V(kt)(2) -> K(kt+1)(2); invariant: K(kt)x2 outstanding
        stage_v(kt);
        __builtin_amdgcn_sched_barrier(0);   // pin: V issues before K issues
        const bool has_next = (kt + 1 < SEQ / 64);
        if (has_next) {
            stage_k(cur ^ 1, kt + 1);
            asm volatile("s_waitcnt vmcnt(4)" ::: "memory");
        } else {
            asm volatile("s_waitcnt vmcnt(2)" ::: "memory");
        }
        __builtin_amdgcn_s_barrier();      // B2: kbuf[cur] (+mask @kt=0) landed

        // S^T = K Q^T (log2 domain), 4 MFMA 32x32x16, C init = mask
        floatx16 s;
#pragma unroll
        for (int g = 0; g < 4; ++g)
#pragma unroll
            for (int r = 0; r < 4; ++r) s[g * 4 + r] = md[g][r];
        {
            const int ko = cur << 12;
            const int krow = kw * 32 + l32;
            const int ksw = krow & 7;
#pragma unroll
            for (int kk = 0; kk < 4; ++kk) {
                const int c = kk * 2 + half;
                short8 a = *(const short8*)&smem[ko + krow * 64 + ((c ^ ksw) * 8)];
                s = __builtin_amdgcn_mfma_f32_32x32x16_bf16(a, b_q[kk], s, 0, 0, 0);
            }
        }

        // p = exp2(min(s,40)); private row-sum; packed stores to p_lds [qrow][key]
        float lsum = 0.f;
        const int psw = prow & 7;
#pragma unroll
        for (int g = 0; g < 4; ++g) {
            const float p0 = fexp2(fminf(s[g * 4 + 0], 40.f));
            const float p1 = fexp2(fminf(s[g * 4 + 1], 40.f));
            const float p2 = fexp2(fminf(s[g * 4 + 2], 40.f));
            const float p3 = fexp2(fminf(s[g * 4 + 3], 40.f));
            lsum += (p0 + p1) + (p2 + p3);
            union { __hip_bfloat162 h[2]; bf16x4 v; } u;
            u.h[0] = __float22bfloat162_rn(make_float2(p0, p1));
            u.h[1] = __float22bfloat162_rn(make_float2(p2, p3));
            const int c = kw * 4 + g;      // chunk of key offset kw*32+8g
            *(bf16x4*)&p_lds[prow * 64 + ((c ^ psw) * 8) + 4 * half] = u.v;
        }
        l_run += lsum;                     // deferred cross-wave combine

        // B3: P visible + V(kt) landed (keep K(kt+1) prefetch in flight)
        asm volatile("s_waitcnt lgkmcnt(0)" ::: "memory");
        if (has_next) {
            asm volatile("s_waitcnt vmcnt(2)" ::: "memory");
        } else {
            asm volatile("s_waitcnt vmcnt(0)" ::: "memory");
        }
        __builtin_amdgcn_s_barrier();

        // O^T += V^T P^T : A=V^T[dh][key], B=P[qrow][key], 4 MFMA 32x32x16
        {
            const int vrow = kw * 32 + l32;    // dh row
            const int vsw = vrow & 7;
#pragma unroll
            for (int kk = 0; kk < 4; ++kk) {
                const int c = kk * 2 + half;
                short8 av = *(const short8*)&smem[8192 + vrow * 64 + ((c ^ vsw) * 8)];
                short8 bp = *(const short8*)&p_lds[prow * 64 + ((c ^ psw) * 8)];
                oacc = __builtin_amdgcn_mfma_f32_32x32x16_bf16(av, bp, oacc, 0, 0, 0);
            }
        }
        cur ^= 1;
    }

    // E1: loop fully done; K-buffer region retires for Ct/l_fin reuse
    asm volatile("" ::: "memory");
    __builtin_amdgcn_s_barrier();

    // cross-half + cross-wave l combine (once): halves share qrow via shfl,
    // kw-pair shares via LDS.
    const float l_mine = l_run + __shfl_xor(l_run, 32);
    l_fin[kw * 64 + prow] = l_mine;        // dup write from both halves, same value
    asm volatile("s_waitcnt lgkmcnt(0)" ::: "memory");
    __builtin_amdgcn_s_barrier();          // E2: l_fin visible

    // epilogue: O^T[dh][qrow] / l -> Ct[qrow][dh] -> coalesced global stores
    const int h = bh & 15, bb = bh >> 4;
    const float rl = 1.f / (l_fin[prow] + l_fin[64 + prow]);
#pragma unroll
    for (int g = 0; g < 4; ++g) {
        bf16x4 p;
        p.x = f2b(oacc[g * 4 + 0] * rl);
        p.y = f2b(oacc[g * 4 + 1] * rl);
        p.z = f2b(oacc[g * 4 + 2] * rl);
        p.w = f2b(oacc[g * 4 + 3] * rl);
        const int dh = kw * 32 + 8 * g + 4 * half;   // row=(reg&3)+8g+4*half
        *(bf16x4*)&Ct[prow * 72 + dh] = p;
    }
    __syncthreads();                       // E3
    {
        const int row = threadIdx.x >> 2, ch = threadIdx.x & 3;
        short8 v0 = *(const short8*)&Ct[row * 72 + ch * 16];
        short8 v1 = *(const short8*)&Ct[row * 72 + ch * 16 + 8];
        short* gp = ctx + ((size_t)(bb * SEQ + qtile * 64 + row)) * DM + h * 64 + ch * 16;
        *(short8*)gp = v0;
        *(short8*)(gp + 8) = v1;
    }
}

// Output GEMM + bias + residual (fp32 out into d_out). 128x64 tile, 2 blocks/CU.
__global__ __launch_bounds__(256) void gemm_o(const short* __restrict__ A,
        const short* __restrict__ B, const float* __restrict__ bo,
        const float* __restrict__ xin, float* __restrict__ out)
{
    __shared__ short As[128 * 32];
    __shared__ short Bs[64 * 32];
    const int m0 = blockIdx.x * 128, n0 = blockIdx.y * 64;
    const int w = threadIdx.x >> 6, lane = threadIdx.x & 63;
    const int l16 = lane & 15, quad = lane >> 4;
    const int wm = w >> 1, wn = w & 1;     // wave: 64 rows x 32 cols

    floatx4 acc[4][2];
#pragma unroll
    for (int i = 0; i < 4; ++i)
#pragma unroll
        for (int j = 0; j < 2; ++j) acc[i][j] = (floatx4){0.f, 0.f, 0.f, 0.f};

    const int c0 = w * 64 + lane;

    for (int kt = 0; kt < DM / 32; ++kt) {
        const int k0 = kt * 32;
        __syncthreads();
        {
            const int ra0 = c0 >> 2,          ca0 = (c0 & 3) * 8;
            const int ra1 = (256 + c0) >> 2,  ca1 = (c0 & 3) * 8;
            async_copy16(A + (size_t)(m0 + ra0) * DM + k0 + ca0, &As[(w * 64) * 8]);
            async_copy16(A + (size_t)(m0 + ra1) * DM + k0 + ca1, &As[(256 + w * 64) * 8]);
            const int rb = c0 >> 2, cb = (c0 & 3) * 8;
            async_copy16(B + (size_t)(n0 + rb) * DM + k0 + cb,   &Bs[(w * 64) * 8]);
        }
        __syncthreads();

        short8 af[4], bf[2];
#pragma unroll
        for (int i = 0; i < 4; ++i)
            af[i] = *(const short8*)&As[(wm * 64 + i * 16 + l16) * 32 + quad * 8];
#pragma unroll
        for (int j = 0; j < 2; ++j)
            bf[j] = *(const short8*)&Bs[(wn * 32 + j * 16 + l16) * 32 + quad * 8];
#pragma unroll
        for (int i = 0; i < 4; ++i)
#pragma unroll
            for (int j = 0; j < 2; ++j)
                acc[i][j] = __builtin_amdgcn_mfma_f32_16x16x32_bf16(af[i], bf[j], acc[i][j], 0, 0, 0);
    }

    const int m_base = m0 + wm * 64 + quad * 4;
#pragma unroll
    for (int j = 0; j < 2; ++j) {
        const int n = n0 + wn * 32 + j * 16 + l16;
        const float bvv = bo[n];
#pragma unroll
        for (int i = 0; i < 4; ++i)
#pragma unroll
            for (int r = 0; r < 4; ++r) {
                const int m = m_base + i * 16 + r;
                const size_t idx = (size_t)m * DM + n;
                out[idx] = acc[i][j][r] + bvv + xin[idx];
            }
    }
}

__global__ __launch_bounds__(256) void ln_kernel(float* __restrict__ y,
        const float* __restrict__ gamma, const float* __restrict__ beta)
{
    const int row = blockIdx.x;
    const int t = threadIdx.x;
    const int wave = t >> 6, lane = t & 63;
    const floatx4 v = ((const floatx4*)(y + (size_t)row * DM))[t];
    float s  = v.x + v.y + v.z + v.w;
    float q2 = v.x * v.x + v.y * v.y + v.z * v.z + v.w * v.w;
#pragma unroll
    for (int off = 1; off < 64; off <<= 1) {
        s  += __shfl_xor(s, off);
        q2 += __shfl_xor(q2, off);
    }
    __shared__ float rs[4], rq[4];
    if (lane == 0) { rs[wave] = s; rq[wave] = q2; }
    __syncthreads();
    const float S  = rs[0] + rs[1] + rs[2] + rs[3];
    const float Q2 = rq[0] + rq[1] + rq[2] + rq[3];
    const float mu = S * (1.f / DM);
    float var = Q2 * (1.f / DM) - mu * mu;
    var = fmaxf(var, 0.f);
    const float rstd = rsqrtf(var + 1e-12f);
    const floatx4 g = ((const floatx4*)gamma)[t];
    const floatx4 bt = ((const floatx4*)beta)[t];
    floatx4 o;
    o.x = (v.x - mu) * rstd * g.x + bt.x;
    o.y = (v.y - mu) * rstd * g.y + bt.y;
    o.z = (v.z - mu) * rstd * g.z + bt.z;
    o.w = (v.w - mu) * rstd * g.w + bt.w;
    ((floatx4*)(y + (size_t)row * DM))[t] = o;
}

extern "C" void kernel_launch(void* const* d_in, const int* in_sizes, int n_in,
                              void* d_out, int out_size, void* d_ws, size_t ws_size,
                              hipStream_t stream) {
    const float* x     = (const float*)d_in[0];
    const float* mask  = (const float*)d_in[1];
    const float* Wq    = (const float*)d_in[2];
    const float* bq    = (const float*)d_in[3];
    const float* Wk    = (const float*)d_in[4];
    const float* bk    = (const float*)d_in[5];
    const float* Wv    = (const float*)d_in[6];
    const float* bv    = (const float*)d_in[7];
    const float* Wo    = (const float*)d_in[8];
    const float* bo    = (const float*)d_in[9];
    const float* gamma = (const float*)d_in[10];
    const float* beta  = (const float*)d_in[11];
    float* out = (float*)d_out;

    const size_t NTOK = (size_t)BATCH * SEQ * DM;       // 4M
    const size_t WSZ  = (size_t)DM * DM;                // 1M
    short* xb   = (short*)d_ws;          // 4M shorts
    short* wqkv = xb + NTOK;             // 3M
    short* wob  = wqkv + 3 * WSZ;        // 1M
    short* qw   = wob + WSZ;             // 4M
    short* kw   = qw + NTOK;             // 4M
    short* vw   = kw + NTOK;             // 4M (free; aliased as ctx)
    short* vtw  = vw + NTOK;             // 4M (V written transposed by gemm_qkv)
    short* ctxw = vw;
    float* maddg = (float*)(vtw + NTOK); // 4096 floats

    dim3 blk(256);
    cvt_all<<<dim3(8194), blk, 0, stream>>>(x, Wq, Wk, Wv, Wo, mask, xb, wqkv, wob, maddg);
    gemm_qkv<<<dim3(32, 24), blk, 0, stream>>>(xb, wqkv, bq, bk, bv, qw, kw, vtw);
    attn_kernel<<<dim3(32 * 32), blk, 0, stream>>>(qw, kw, vtw, maddg, ctxw);
    gemm_o<<<dim3(32, 16), blk, 0, stream>>>(ctxw, wob, bo, x, out);
    ln_kernel<<<BATCH * SEQ, blk, 0, stream>>>(out, gamma, beta);
}

// Round 11
// 219.029 us; speedup vs baseline: 1.0863x; 1.0315x over previous
//
#include <hip/hip_runtime.h>
#include <hip/hip_bf16.h>

#define DM   1024
#define HEADS 16
#define DH    64
#define SEQ  2048
#define BATCH   2
#define LOG2E 1.44269504088896f

typedef __attribute__((ext_vector_type(8))) short short8;
typedef __attribute__((ext_vector_type(4))) short bf16x4;
typedef __attribute__((ext_vector_type(4))) float floatx4;
typedef __attribute__((ext_vector_type(16))) float floatx16;

__device__ __forceinline__ short f2b(float f) {
    union { float f; unsigned u; } v; v.f = f;
    unsigned r = v.u + 0x7FFFu + ((v.u >> 16) & 1u);
    return (short)(r >> 16);
}

#if __has_builtin(__builtin_amdgcn_exp2f)
__device__ __forceinline__ float fexp2(float x) { return __builtin_amdgcn_exp2f(x); }
#else
__device__ __forceinline__ float fexp2(float x) { return exp2f(x); }
#endif

__device__ __forceinline__ void async_copy16(const short* gsrc, short* ldst) {
    __builtin_amdgcn_global_load_lds(
        (const __attribute__((address_space(1))) void*)gsrc,
        (__attribute__((address_space(3))) void*)ldst,
        16, 0, 0);
}

// Fused fp32->bf16 conversion of x, Wq, Wk, Wv, Wo + mask-add table (log2 domain).
__global__ __launch_bounds__(256) void cvt_all(const float* __restrict__ x,
        const float* __restrict__ wq, const float* __restrict__ wk,
        const float* __restrict__ wv, const float* __restrict__ wo,
        const float* __restrict__ mask,
        short* __restrict__ xb, short* __restrict__ wqkv, short* __restrict__ wob,
        float* __restrict__ maddg)
{
    const int b = blockIdx.x;
    if (b >= 8192) {            // mask prep: maddg = (1-mask) * (-1e5 * log2e)
        const int bb = b - 8192;
        const float* mrow = mask + (size_t)bb * SEQ;
        float* mg = maddg + (size_t)bb * SEQ;
#pragma unroll
        for (int i = 0; i < 8; ++i) {
            const int idx = threadIdx.x * 8 + i;
            mg[idx] = (1.f - mrow[idx]) * (-100000.f * LOG2E);
        }
        return;
    }
    const float* src; short* dst; int idx;
    if (b < 4096)      { src = x;  dst = xb;                idx = b; }
    else if (b < 5120) { src = wq; dst = wqkv;              idx = b - 4096; }
    else if (b < 6144) { src = wk; dst = wqkv + (1 << 20);  idx = b - 5120; }
    else if (b < 7168) { src = wv; dst = wqkv + (2 << 20);  idx = b - 6144; }
    else               { src = wo; dst = wob;               idx = b - 7168; }
    const int i = idx * 256 + threadIdx.x;
    floatx4 v = ((const floatx4*)src)[i];
    bf16x4 o;
    o.x = f2b(v.x); o.y = f2b(v.y); o.z = f2b(v.z); o.w = f2b(v.w);
    ((bf16x4*)dst)[i] = o;
}

// Fused QKV GEMM (m97 structure, 128x128 tile, BK=32). B rows: Wq|Wk|Wv.
// Q pre-scaled by 0.125*log2e (exp2-domain softmax). Q/K/V in [b,h,s,dh].
// ROUND-10: REVERTED to the R4-verified scatter epilogue + separate
// transpose_v. Ledger across verified rounds: unfused non-attn ≈147-150 µs,
// fused ≈160.5 µs (tight, 4 samples) — and R10's coalesced-store fix did NOT
// recover it, so the fusion itself (not the store pattern) costs ~13 µs.
// This round tests that theory cleanly: all components individually verified.
__global__ __launch_bounds__(256) void gemm_qkv(const short* __restrict__ A,
        const short* __restrict__ B,
        const float* __restrict__ bq, const float* __restrict__ bk,
        const float* __restrict__ bv,
        short* __restrict__ qw, short* __restrict__ kw, short* __restrict__ vw)
{
    __shared__ short As[128 * 32];
    __shared__ short Bs[128 * 32];
    const int m0 = blockIdx.x * 128, n0 = blockIdx.y * 128;
    const int w = threadIdx.x >> 6, lane = threadIdx.x & 63;
    const int l16 = lane & 15, quad = lane >> 4;
    const int wm = w >> 1, wn = w & 1;
    const int lr = lane >> 2, lc = (lane & 3) * 8;

    floatx4 acc[4][4];
#pragma unroll
    for (int i = 0; i < 4; ++i)
#pragma unroll
        for (int j = 0; j < 4; ++j) acc[i][j] = (floatx4){0.f, 0.f, 0.f, 0.f};

    for (int kt = 0; kt < DM / 32; ++kt) {
        const int k0 = kt * 32;
        __syncthreads();
        async_copy16(A + (size_t)(m0 + w * 32 + lr) * DM + k0 + lc,      &As[w * 1024]);
        async_copy16(A + (size_t)(m0 + w * 32 + 16 + lr) * DM + k0 + lc, &As[w * 1024 + 512]);
        async_copy16(B + (size_t)(n0 + w * 32 + lr) * DM + k0 + lc,      &Bs[w * 1024]);
        async_copy16(B + (size_t)(n0 + w * 32 + 16 + lr) * DM + k0 + lc, &Bs[w * 1024 + 512]);
        __syncthreads();

        short8 af[4], bf[4];
#pragma unroll
        for (int i = 0; i < 4; ++i)
            af[i] = *(const short8*)&As[(wm * 64 + i * 16 + l16) * 32 + quad * 8];
#pragma unroll
        for (int j = 0; j < 4; ++j)
            bf[j] = *(const short8*)&Bs[(wn * 64 + j * 16 + l16) * 32 + quad * 8];
#pragma unroll
        for (int i = 0; i < 4; ++i)
#pragma unroll
            for (int j = 0; j < 4; ++j)
                acc[i][j] = __builtin_amdgcn_mfma_f32_16x16x32_bf16(af[i], bf[j], acc[i][j], 0, 0, 0);
    }

    const int m_base = m0 + wm * 64 + quad * 4;
#pragma unroll
    for (int j = 0; j < 4; ++j) {
        const int nb = n0 + wn * 64 + j * 16;
        const int t = nb >> 10;
        const int nn = (nb & 1023) + l16;
        const int h = nn >> 6, dh = nn & 63;
        const float* bias = (t == 0) ? bq : (t == 1) ? bk : bv;
        short* dst = (t == 0) ? qw : (t == 1) ? kw : vw;
        const float mulf = (t == 0) ? (0.125f * LOG2E) : 1.0f;
        const float bvv = bias[nn];
#pragma unroll
        for (int i = 0; i < 4; ++i)
#pragma unroll
            for (int r = 0; r < 4; ++r) {
                const int m = m_base + i * 16 + r;
                const int b = m >> 11, s = m & (SEQ - 1);
                dst[(((size_t)(b * HEADS + h)) * SEQ + s) * DH + dh] =
                    f2b((acc[i][j][r] + bvv) * mulf);
            }
    }
}

// v [b,h,s,dh] -> vt [b,h,dh,s], 64x64 LDS tiles (coalesced both sides)
__global__ __launch_bounds__(256) void transpose_v(const short* __restrict__ v,
                                                   short* __restrict__ vt)
{
    __shared__ short tl[64][72];
    const int st = blockIdx.x;
    const int bh = blockIdx.y;
    const int t = threadIdx.x;
    const int row = t >> 2, off = (t & 3) * 16;
    const short* vp = v + ((size_t)bh * SEQ + st * 64 + row) * DH + off;
    *(short8*)&tl[row][off]     = *(const short8*)vp;
    *(short8*)&tl[row][off + 8] = *(const short8*)(vp + 8);
    __syncthreads();
    short8 o0, o1;
#pragma unroll
    for (int j = 0; j < 8; ++j) { o0[j] = tl[off + j][row]; o1[j] = tl[off + 8 + j][row]; }
    short* op = vt + ((size_t)bh * DH + row) * SEQ + st * 64 + off;
    *(short8*)op = o0;
    *(short8*)(op + 8) = o1;
}

// Flash attention, 32x32x16 MFMA formulation.
// (R9/R10-verified: 65.7-66.2 µs. Mask row staged once into LDS; single-
// buffered V; double-buffered K with counted vmcnt FIFO; occ ~31%.)
// Arena: K2(16K) + V(8K) + P(8K) + mask(8K) = 40960B. Ct+l_fin alias K bufs.
// Layouts: A/B 32x32x16: m(n)=lane&31, k=8*(lane>>5)+j. C/D: col=lane&31,
// row=(reg&3)+8*(reg>>2)+4*(lane>>5)  [m74/m101-verified].
__global__ __launch_bounds__(256) void attn_kernel(const short* __restrict__ q,
        const short* __restrict__ k, const short* __restrict__ vt,
        const float* __restrict__ maddg, short* __restrict__ ctx)
{
    const int id    = blockIdx.x;
    const int qtile = id >> 5;             // id = qtile*32 + bh
    const int bh    = id & 31;
    const int bidx  = bh >> 4;
    const int wave = threadIdx.x >> 6, lane = threadIdx.x & 63;
    const int l32 = lane & 31, half = lane >> 5;
    const int kw = wave & 1, qw = wave >> 1;   // S^T: keys kw*32.., qrows qw*32..
                                               // PV: dh kw*32.., qrows qw*32..

    __shared__ __align__(16) short smem[20480];
    short* p_lds    = smem + 12288;
    float* mask_lds = (float*)(smem + 16384);
    short* Ct       = smem;
    float* l_fin    = (float*)(smem + 4608);

    const short* kbase0 = k  + (size_t)bh * SEQ * DH;
    const short* vbase0 = vt + (size_t)bh * DH * SEQ;
    const float* mrow   = maddg + (size_t)bidx * SEQ;

    // Q B-frags: B[n=qrow=l32][k=dh = kk*16 + half*8 + j]
    const int qrow = qtile * 64 + qw * 32 + l32;
    const short* qbase = q + ((size_t)bh * SEQ + qrow) * DH;
    short8 b_q[4];
#pragma unroll
    for (int kk = 0; kk < 4; ++kk)
        b_q[kk] = *(const short8*)(qbase + kk * 16 + half * 8);

    floatx16 oacc;
#pragma unroll
    for (int r = 0; r < 16; ++r) oacc[r] = 0.f;
    float l_run = 0.f;

    // staging geometry: 512 chunks/tile, 256 threads -> 2 chunks/thread/array
    int srw[2], gg[2];
#pragma unroll
    for (int i = 0; i < 2; ++i) {
        const int slot = i * 256 + wave * 64 + lane;
        srw[i] = slot >> 3;
        gg[i]  = (slot & 7) ^ (srw[i] & 7);
    }

    const int prow = qw * 32 + l32;        // this lane's qrow (local 0..63)

    auto stage_k = [&](int buf, int kt) {
        const short* kbase = kbase0 + (size_t)(kt * 64) * DH;
        const int ko = buf << 12;
#pragma unroll
        for (int i = 0; i < 2; ++i)
            async_copy16(kbase + srw[i] * DH + gg[i] * 8,
                         &smem[ko + (i * 256 + wave * 64) * 8]);
    };
    auto stage_v = [&](int kt) {
        const short* vbase = vbase0 + kt * 64;
#pragma unroll
        for (int i = 0; i < 2; ++i)
            async_copy16(vbase + (size_t)srw[i] * SEQ + gg[i] * 8,
                         &smem[8192 + (i * 256 + wave * 64) * 8]);
    };

    // prologue: mask row (2 copies/thread) + K tile 0 (2 copies/thread).
#pragma unroll
    for (int i = 0; i < 2; ++i)
        async_copy16((const short*)mrow + (i * 256 + threadIdx.x) * 8,
                     &smem[16384 + (i * 256 + wave * 64) * 8]);
    stage_k(0, 0);

    int cur = 0;
    for (int kt = 0; kt < SEQ / 64; ++kt) {
        // B1: prev-iter reads of vbuf / p_lds complete; kbuf[cur^1] retired
        asm volatile("" ::: "memory");
        __builtin_amdgcn_s_barrier();

        // mask C-init from LDS (broadcast ds_read_b128 — not in vmcnt FIFO)
        floatx4 md[4];
#pragma unroll
        for (int g = 0; g < 4; ++g)
            md[g] = *(const floatx4*)&mask_lds[kt * 64 + kw * 32 + 8 * g + 4 * half];

        // staging FIFO: V(kt)(2) -> K(kt+1)(2); invariant: K(kt)x2 outstanding
        stage_v(kt);
        __builtin_amdgcn_sched_barrier(0);   // pin: V issues before K issues
        const bool has_next = (kt + 1 < SEQ / 64);
        if (has_next) {
            stage_k(cur ^ 1, kt + 1);
            asm volatile("s_waitcnt vmcnt(4)" ::: "memory");
        } else {
            asm volatile("s_waitcnt vmcnt(2)" ::: "memory");
        }
        __builtin_amdgcn_s_barrier();      // B2: kbuf[cur] (+mask @kt=0) landed

        // S^T = K Q^T (log2 domain), 4 MFMA 32x32x16, C init = mask
        floatx16 s;
#pragma unroll
        for (int g = 0; g < 4; ++g)
#pragma unroll
            for (int r = 0; r < 4; ++r) s[g * 4 + r] = md[g][r];
        {
            const int ko = cur << 12;
            const int krow = kw * 32 + l32;
            const int ksw = krow & 7;
#pragma unroll
            for (int kk = 0; kk < 4; ++kk) {
                const int c = kk * 2 + half;
                short8 a = *(const short8*)&smem[ko + krow * 64 + ((c ^ ksw) * 8)];
                s = __builtin_amdgcn_mfma_f32_32x32x16_bf16(a, b_q[kk], s, 0, 0, 0);
            }
        }

        // p = exp2(min(s,40)); private row-sum; packed stores to p_lds [qrow][key]
        float lsum = 0.f;
        const int psw = prow & 7;
#pragma unroll
        for (int g = 0; g < 4; ++g) {
            const float p0 = fexp2(fminf(s[g * 4 + 0], 40.f));
            const float p1 = fexp2(fminf(s[g * 4 + 1], 40.f));
            const float p2 = fexp2(fminf(s[g * 4 + 2], 40.f));
            const float p3 = fexp2(fminf(s[g * 4 + 3], 40.f));
            lsum += (p0 + p1) + (p2 + p3);
            union { __hip_bfloat162 h[2]; bf16x4 v; } u;
            u.h[0] = __float22bfloat162_rn(make_float2(p0, p1));
            u.h[1] = __float22bfloat162_rn(make_float2(p2, p3));
            const int c = kw * 4 + g;      // chunk of key offset kw*32+8g
            *(bf16x4*)&p_lds[prow * 64 + ((c ^ psw) * 8) + 4 * half] = u.v;
        }
        l_run += lsum;                     // deferred cross-wave combine

        // B3: P visible + V(kt) landed (keep K(kt+1) prefetch in flight)
        asm volatile("s_waitcnt lgkmcnt(0)" ::: "memory");
        if (has_next) {
            asm volatile("s_waitcnt vmcnt(2)" ::: "memory");
        } else {
            asm volatile("s_waitcnt vmcnt(0)" ::: "memory");
        }
        __builtin_amdgcn_s_barrier();

        // O^T += V^T P^T : A=V^T[dh][key], B=P[qrow][key], 4 MFMA 32x32x16
        {
            const int vrow = kw * 32 + l32;    // dh row
            const int vsw = vrow & 7;
#pragma unroll
            for (int kk = 0; kk < 4; ++kk) {
                const int c = kk * 2 + half;
                short8 av = *(const short8*)&smem[8192 + vrow * 64 + ((c ^ vsw) * 8)];
                short8 bp = *(const short8*)&p_lds[prow * 64 + ((c ^ psw) * 8)];
                oacc = __builtin_amdgcn_mfma_f32_32x32x16_bf16(av, bp, oacc, 0, 0, 0);
            }
        }
        cur ^= 1;
    }

    // E1: loop fully done; K-buffer region retires for Ct/l_fin reuse
    asm volatile("" ::: "memory");
    __builtin_amdgcn_s_barrier();

    // cross-half + cross-wave l combine (once): halves share qrow via shfl,
    // kw-pair shares via LDS.
    const float l_mine = l_run + __shfl_xor(l_run, 32);
    l_fin[kw * 64 + prow] = l_mine;        // dup write from both halves, same value
    asm volatile("s_waitcnt lgkmcnt(0)" ::: "memory");
    __builtin_amdgcn_s_barrier();          // E2: l_fin visible

    // epilogue: O^T[dh][qrow] / l -> Ct[qrow][dh] -> coalesced global stores
    const int h = bh & 15, bb = bh >> 4;
    const float rl = 1.f / (l_fin[prow] + l_fin[64 + prow]);
#pragma unroll
    for (int g = 0; g < 4; ++g) {
        bf16x4 p;
        p.x = f2b(oacc[g * 4 + 0] * rl);
        p.y = f2b(oacc[g * 4 + 1] * rl);
        p.z = f2b(oacc[g * 4 + 2] * rl);
        p.w = f2b(oacc[g * 4 + 3] * rl);
        const int dh = kw * 32 + 8 * g + 4 * half;   // row=(reg&3)+8g+4*half
        *(bf16x4*)&Ct[prow * 72 + dh] = p;
    }
    __syncthreads();                       // E3
    {
        const int row = threadIdx.x >> 2, ch = threadIdx.x & 3;
        short8 v0 = *(const short8*)&Ct[row * 72 + ch * 16];
        short8 v1 = *(const short8*)&Ct[row * 72 + ch * 16 + 8];
        short* gp = ctx + ((size_t)(bb * SEQ + qtile * 64 + row)) * DM + h * 64 + ch * 16;
        *(short8*)gp = v0;
        *(short8*)(gp + 8) = v1;
    }
}

// Output GEMM + bias + residual (fp32 out into d_out). 128x64 tile, 2 blocks/CU.
__global__ __launch_bounds__(256) void gemm_o(const short* __restrict__ A,
        const short* __restrict__ B, const float* __restrict__ bo,
        const float* __restrict__ xin, float* __restrict__ out)
{
    __shared__ short As[128 * 32];
    __shared__ short Bs[64 * 32];
    const int m0 = blockIdx.x * 128, n0 = blockIdx.y * 64;
    const int w = threadIdx.x >> 6, lane = threadIdx.x & 63;
    const int l16 = lane & 15, quad = lane >> 4;
    const int wm = w >> 1, wn = w & 1;     // wave: 64 rows x 32 cols

    floatx4 acc[4][2];
#pragma unroll
    for (int i = 0; i < 4; ++i)
#pragma unroll
        for (int j = 0; j < 2; ++j) acc[i][j] = (floatx4){0.f, 0.f, 0.f, 0.f};

    const int c0 = w * 64 + lane;

    for (int kt = 0; kt < DM / 32; ++kt) {
        const int k0 = kt * 32;
        __syncthreads();
        {
            const int ra0 = c0 >> 2,          ca0 = (c0 & 3) * 8;
            const int ra1 = (256 + c0) >> 2,  ca1 = (c0 & 3) * 8;
            async_copy16(A + (size_t)(m0 + ra0) * DM + k0 + ca0, &As[(w * 64) * 8]);
            async_copy16(A + (size_t)(m0 + ra1) * DM + k0 + ca1, &As[(256 + w * 64) * 8]);
            const int rb = c0 >> 2, cb = (c0 & 3) * 8;
            async_copy16(B + (size_t)(n0 + rb) * DM + k0 + cb,   &Bs[(w * 64) * 8]);
        }
        __syncthreads();

        short8 af[4], bf[2];
#pragma unroll
        for (int i = 0; i < 4; ++i)
            af[i] = *(const short8*)&As[(wm * 64 + i * 16 + l16) * 32 + quad * 8];
#pragma unroll
        for (int j = 0; j < 2; ++j)
            bf[j] = *(const short8*)&Bs[(wn * 32 + j * 16 + l16) * 32 + quad * 8];
#pragma unroll
        for (int i = 0; i < 4; ++i)
#pragma unroll
            for (int j = 0; j < 2; ++j)
                acc[i][j] = __builtin_amdgcn_mfma_f32_16x16x32_bf16(af[i], bf[j], acc[i][j], 0, 0, 0);
    }

    const int m_base = m0 + wm * 64 + quad * 4;
#pragma unroll
    for (int j = 0; j < 2; ++j) {
        const int n = n0 + wn * 32 + j * 16 + l16;
        const float bvv = bo[n];
#pragma unroll
        for (int i = 0; i < 4; ++i)
#pragma unroll
            for (int r = 0; r < 4; ++r) {
                const int m = m_base + i * 16 + r;
                const size_t idx = (size_t)m * DM + n;
                out[idx] = acc[i][j][r] + bvv + xin[idx];
            }
    }
}

__global__ __launch_bounds__(256) void ln_kernel(float* __restrict__ y,
        const float* __restrict__ gamma, const float* __restrict__ beta)
{
    const int row = blockIdx.x;
    const int t = threadIdx.x;
    const int wave = t >> 6, lane = t & 63;
    const floatx4 v = ((const floatx4*)(y + (size_t)row * DM))[t];
    float s  = v.x + v.y + v.z + v.w;
    float q2 = v.x * v.x + v.y * v.y + v.z * v.z + v.w * v.w;
#pragma unroll
    for (int off = 1; off < 64; off <<= 1) {
        s  += __shfl_xor(s, off);
        q2 += __shfl_xor(q2, off);
    }
    __shared__ float rs[4], rq[4];
    if (lane == 0) { rs[wave] = s; rq[wave] = q2; }
    __syncthreads();
    const float S  = rs[0] + rs[1] + rs[2] + rs[3];
    const float Q2 = rq[0] + rq[1] + rq[2] + rq[3];
    const float mu = S * (1.f / DM);
    float var = Q2 * (1.f / DM) - mu * mu;
    var = fmaxf(var, 0.f);
    const float rstd = rsqrtf(var + 1e-12f);
    const floatx4 g = ((const floatx4*)gamma)[t];
    const floatx4 bt = ((const floatx4*)beta)[t];
    floatx4 o;
    o.x = (v.x - mu) * rstd * g.x + bt.x;
    o.y = (v.y - mu) * rstd * g.y + bt.y;
    o.z = (v.z - mu) * rstd * g.z + bt.z;
    o.w = (v.w - mu) * rstd * g.w + bt.w;
    ((floatx4*)(y + (size_t)row * DM))[t] = o;
}

extern "C" void kernel_launch(void* const* d_in, const int* in_sizes, int n_in,
                              void* d_out, int out_size, void* d_ws, size_t ws_size,
                              hipStream_t stream) {
    const float* x     = (const float*)d_in[0];
    const float* mask  = (const float*)d_in[1];
    const float* Wq    = (const float*)d_in[2];
    const float* bq    = (const float*)d_in[3];
    const float* Wk    = (const float*)d_in[4];
    const float* bk    = (const float*)d_in[5];
    const float* Wv    = (const float*)d_in[6];
    const float* bv    = (const float*)d_in[7];
    const float* Wo    = (const float*)d_in[8];
    const float* bo    = (const float*)d_in[9];
    const float* gamma = (const float*)d_in[10];
    const float* beta  = (const float*)d_in[11];
    float* out = (float*)d_out;

    const size_t NTOK = (size_t)BATCH * SEQ * DM;       // 4M
    const size_t WSZ  = (size_t)DM * DM;                // 1M
    short* xb   = (short*)d_ws;          // 4M shorts
    short* wqkv = xb + NTOK;             // 3M
    short* wob  = wqkv + 3 * WSZ;        // 1M
    short* qw   = wob + WSZ;             // 4M
    short* kw   = qw + NTOK;             // 4M
    short* vw   = kw + NTOK;             // 4M (natural V; aliased as ctx)
    short* vtw  = vw + NTOK;             // 4M (V transposed)
    short* ctxw = vw;
    float* maddg = (float*)(vtw + NTOK); // 4096 floats

    dim3 blk(256);
    cvt_all<<<dim3(8194), blk, 0, stream>>>(x, Wq, Wk, Wv, Wo, mask, xb, wqkv, wob, maddg);
    gemm_qkv<<<dim3(32, 24), blk, 0, stream>>>(xb, wqkv, bq, bk, bv, qw, kw, vw);
    transpose_v<<<dim3(SEQ / 64, BATCH * HEADS), blk, 0, stream>>>(vw, vtw);
    attn_kernel<<<dim3(32 * 32), blk, 0, stream>>>(qw, kw, vtw, maddg, ctxw);
    gemm_o<<<dim3(32, 16), blk, 0, stream>>>(ctxw, wob, bo, x, out);
    ln_kernel<<<BATCH * SEQ, blk, 0, stream>>>(out, gamma, beta);
}